// Round 4
// baseline (1159.822 us; speedup 1.0000x reference)
//
#include <hip/hip_runtime.h>
#include <hip/hip_bf16.h>

typedef __hip_bfloat16 bf16;
typedef short bf16x8 __attribute__((ext_vector_type(8)));
typedef float f32x4 __attribute__((ext_vector_type(4)));

#define DEV __device__ __forceinline__

DEV float bf2f(bf16 v) { return __bfloat162float(v); }
DEV bf16 f2bf(float v) { return __float2bfloat16(v); }
DEV unsigned short bfr(float f) {
  bf16 h = __float2bfloat16(f);
  return *reinterpret_cast<unsigned short*>(&h);
}
DEV float shf(unsigned short u) {
  unsigned int x = ((unsigned int)u) << 16;
  return *reinterpret_cast<float*>(&x);
}
DEV float gelu_exact(float x) { return 0.5f * x * (1.0f + erff(x * 0.70710678118654752f)); }

DEV float ldw(const void* p, long i, int isb) {
  return isb ? __bfloat162float(((const bf16*)p)[i]) : ((const float*)p)[i];
}

// ---------------- dtype detection + flag constants ----------------
__global__ void k_detect(const unsigned short* __restrict__ u, int* __restrict__ flag) {
  __shared__ int bad;
  if (threadIdx.x == 0) bad = 0;
  __syncthreads();
  for (int i = threadIdx.x; i < 8192; i += 256) {
    int expo = (u[i] >> 7) & 0xFF;
    if (expo >= 138) atomicOr(&bad, 1);
  }
  __syncthreads();
  if (threadIdx.x == 0) *flag = bad ? 0 : 1;
}
__global__ void k_setone(int* p) { *p = 1; }

// ---------------- convert (bf16|fp32) -> fp32 ----------------
__global__ void k_cvt(const void* __restrict__ s, float* __restrict__ d, int n,
                      const int* __restrict__ fl) {
  int isb = *fl;
  int i = blockIdx.x * blockDim.x + threadIdx.x;
  if (i < n) d[i] = ldw(s, i, isb);
}

__global__ void k_zerosh(unsigned short* __restrict__ p, int n8) {
  int i = blockIdx.x * blockDim.x + threadIdx.x;
  if (i < n8) { uint4 z = {0, 0, 0, 0}; *(uint4*)(p + (long)i * 8) = z; }
}

// tokenizer weight [192][49] (at element offset 9408) -> bf16 [192][64] zero-padded
__global__ void k_padtokw(const void* __restrict__ tw, bf16* __restrict__ dst,
                          const int* __restrict__ fl) {
  int isb = *fl;
  int i = blockIdx.x * blockDim.x + threadIdx.x;
  if (i >= 12288) return;
  int n = i >> 6, k = i & 63;
  float v = (k < 49) ? ldw(tw, 9408 + (long)n * 49 + k, isb) : 0.0f;
  dst[i] = f2bf(v);
}

// conv weight pack: dst[s][np][icp] bf16 from src [OC][ICT][9], channel remap feats|warp|flow|0
__global__ void k_packw(const void* __restrict__ src, bf16* __restrict__ dst,
                        int OC, int C, int ICT, int NP, int ICP, int n,
                        const int* __restrict__ fl) {
  int isb = *fl;
  int i = blockIdx.x * blockDim.x + threadIdx.x;
  if (i >= n) return;
  int s = i / (NP * ICP);
  int r = i - s * NP * ICP;
  int oc = r / ICP, icp = r - oc * ICP;
  float v = 0.0f;
  if (oc < OC) {
    int ic = -1;
    if (icp < C) ic = icp;
    else if (icp < 2 * C) ic = icp - C + C + 2;
    else if (icp < 2 * C + 2) ic = icp - 2 * C + C;
    if (ic >= 0 && ic < ICT) v = ldw(src, ((long)oc * ICT + ic) * 9 + s, isb);
  }
  dst[i] = f2bf(v);
}

// feats [F][C][HW] -> pixel-major bf16 [F][HW][C]; one thread per 8-channel group
__global__ void k_trans_feats(const void* __restrict__ in, bf16* __restrict__ Fp,
                              int F, int C, int HW, const int* __restrict__ fl) {
  int isb = *fl;
  int cpg = C >> 3;
  int n = F * HW * cpg;
  int i = blockIdx.x * blockDim.x + threadIdx.x;
  if (i >= n) return;
  int p = i % HW;
  int rem = i / HW;
  int c8 = rem % cpg;
  int f = rem / cpg;
  long base = (long)f * C * HW + (long)(c8 * 8) * HW + p;
  union { unsigned short u[8]; uint4 v; } pk;
#pragma unroll
  for (int j = 0; j < 8; ++j) pk.u[j] = bfr(ldw(in, base + (long)j * HW, isb));
  *(uint4*)((unsigned short*)Fp + ((long)f * HW + p) * C + c8 * 8) = pk.v;
}

// ---------------- decoder conv1: ONE-SHOT staged MFMA implicit-GEMM 3x3 + fused warp --
// Full A-tile (64 px + halo, all ICP channels) and double-buffered W slice resident in
// LDS. One burst of feats loads + desc loads + W(0); barrier; chunked bilinear gathers;
// barrier; then 9*NK MFMAs with tiny in-loop W prefetch. BM=64, BN=16, 4 waves.
template <int C, int ICP, int ICPP, int NOUT, int WW, int LGW>
__global__ __launch_bounds__(256) void k_conv_osa(
    const bf16* __restrict__ Fp, const float* __restrict__ flow,
    const bf16* __restrict__ Wp, const float* __restrict__ bias,
    bf16* __restrict__ out) {
  constexpr int HH = WW, HW = WW * WW;
  constexpr int CW = (WW < 64) ? WW : 64;
  constexpr int LGCW = (CW == 64) ? 6 : 5;
  constexpr int RO = 64 / CW;
  constexpr int ACW = CW + 2;
  constexpr int APX = (RO + 2) * ACW;
  constexpr int NK = ICP / 32;
  constexpr int CG = C / 8;
  constexpr int NFEAT = APX * CG;
  constexpr int NFI = (NFEAT + 255) / 256;
  constexpr int TG = (ICP - 2 * C) / 8;
  __shared__ unsigned short As[APX][ICPP];
  __shared__ unsigned short Ws[2][144][40];
  __shared__ int doff[APX][4];
  __shared__ float dwt[APX][4];
  int tid = threadIdx.x;
  int wv = tid >> 6, ln = tid & 63, quad = ln >> 4, l16 = ln & 15;
  int n0 = blockIdx.x * 16, m0 = blockIdx.y * 64, b = blockIdx.z;
  int py0 = m0 >> LGW;
  const unsigned short* fcur = (const unsigned short*)Fp + (long)b * HW * C;
  const unsigned short* fnxt = (const unsigned short*)Fp + (long)(b + 1) * HW * C;
  const float* fl = flow + (long)b * 2 * HW;
  uint4 wrg[3];
  auto ldWs = [&](int kc) {
#pragma unroll
    for (int j = 0; j < 3; ++j) {
      int i = tid + j * 256;
      if (i < 576) {
        int r = i >> 2, c4 = i & 3;
        int s = r >> 4, nl = r & 15;
        wrg[j] = *(const uint4*)((const unsigned short*)Wp +
                 ((long)s * NOUT + n0 + nl) * ICP + kc * 32 + c4 * 8);
      }
    }
  };
  auto stWs = [&](int bsel) {
#pragma unroll
    for (int j = 0; j < 3; ++j) {
      int i = tid + j * 256;
      if (i < 576) {
        int r = i >> 2, c4 = i & 3;
        *(uint4*)&Ws[bsel][r][c4 * 8] = wrg[j];
      }
    }
  };
  // ---- phase 1: feats burst + W(0) burst + per-pixel descriptors ----
  uint4 fva[NFI];
  int fap[NFI], fcg[NFI];
  bool fok[NFI];
#pragma unroll
  for (int j = 0; j < NFI; ++j) {
    int i = tid + j * 256;
    bool v = i < NFEAT;
    int ap = v ? (i / CG) : 0;
    int cg = i & (CG - 1);
    fap[j] = ap; fcg[j] = cg; fok[j] = v;
    int sr = ap / ACW, sc = ap - sr * ACW;
    int py = py0 + sr - 1, px = sc - 1;
    bool in = v && py >= 0 && py < HH && px >= 0 && px < WW;
    uint4 z = {0, 0, 0, 0};
    fva[j] = in ? *(const uint4*)(fcur + (long)(py * WW + px) * C + cg * 8) : z;
  }
  ldWs(0);
  if (tid < APX) {
    int ap = tid;
    int sr = ap / ACW, sc = ap - sr * ACW;
    int py = py0 + sr - 1, px = sc - 1;
    bool in = py >= 0 && py < HH && px >= 0 && px < WW;
    int p = in ? (py * WW + px) : 0;
    float fx = in ? fl[p] : 0.0f, fy = in ? fl[HW + p] : 0.0f;
    float x = fminf(fmaxf((float)px + fx, 0.0f), (float)(WW - 1));
    float y = fminf(fmaxf((float)py + fy, 0.0f), (float)(HH - 1));
    int x0 = (int)floorf(x), y0 = (int)floorf(y);
    int x1 = min(x0 + 1, WW - 1), y1 = min(y0 + 1, HH - 1);
    float wx = x - (float)x0, wy = y - (float)y0;
    float q00 = in ? (1 - wx) * (1 - wy) : 0.0f, q01 = in ? wx * (1 - wy) : 0.0f;
    float q10 = in ? (1 - wx) * wy : 0.0f,       q11 = in ? wx * wy : 0.0f;
    doff[ap][0] = (y0 * WW + x0) * C; doff[ap][1] = (y0 * WW + x1) * C;
    doff[ap][2] = (y1 * WW + x0) * C; doff[ap][3] = (y1 * WW + x1) * C;
    dwt[ap][0] = q00; dwt[ap][1] = q01; dwt[ap][2] = q10; dwt[ap][3] = q11;
#pragma unroll
    for (int t = 0; t < TG; ++t) {
      union { unsigned short u[8]; uint4 v; } o = { .v = {0, 0, 0, 0} };
      if (t == 0 && in) { o.u[0] = bfr(fx); o.u[1] = bfr(fy); }
      *(uint4*)&As[ap][2 * C + t * 8] = o.v;
    }
  }
#pragma unroll
  for (int j = 0; j < NFI; ++j)
    if (fok[j]) *(uint4*)&As[fap[j]][fcg[j] * 8] = fva[j];
  stWs(0);
  __syncthreads();
  // ---- phase 2: bilinear gathers (chunks of 3 groups -> 12 loads in flight) ----
#pragma unroll
  for (int jc = 0; jc < (NFI + 2) / 3; ++jc) {
    uint4 q[3][4];
    float w4[3][4];
    int ga[3], gc[3];
    bool gv[3];
#pragma unroll
    for (int u = 0; u < 3; ++u) {
      int j = jc * 3 + u;
      int i = tid + j * 256;
      bool v = (j < NFI) && (i < NFEAT);
      gv[u] = v;
      int ap = v ? (i / CG) : 0;
      int cg = i & (CG - 1);
      ga[u] = ap; gc[u] = cg;
#pragma unroll
      for (int e = 0; e < 4; ++e) {
        w4[u][e] = dwt[ap][e];
        q[u][e] = *(const uint4*)(fnxt + doff[ap][e] + cg * 8);
      }
    }
#pragma unroll
    for (int u = 0; u < 3; ++u) {
      if (!gv[u]) continue;
      union { unsigned short s[8]; uint4 v; } a0 = {.v = q[u][0]}, a1 = {.v = q[u][1]},
                                              a2 = {.v = q[u][2]}, a3 = {.v = q[u][3]}, o;
#pragma unroll
      for (int e = 0; e < 8; ++e)
        o.s[e] = bfr(shf(a0.s[e]) * w4[u][0] + shf(a1.s[e]) * w4[u][1] +
                     shf(a2.s[e]) * w4[u][2] + shf(a3.s[e]) * w4[u][3]);
      *(uint4*)&As[ga[u]][C + gc[u] * 8] = o.v;
    }
  }
  __syncthreads();
  // ---- phase 3: MFMA loop (W prefetch hidden under MFMAs) ----
  int pl = wv * 16 + l16;
  int prow = pl >> LGCW, pcol = pl & (CW - 1);
  f32x4 ac0 = {}, ac1 = {}, ac2 = {};
  for (int kc = 0; kc < NK; ++kc) {
    if (kc + 1 < NK) ldWs(kc + 1);
    int cb = kc & 1;
#pragma unroll
    for (int s = 0; s < 9; ++s) {
      int ky = s / 3, kx = s - ky * 3;
      bf16x8 af = *(const bf16x8*)&As[(prow + ky) * ACW + pcol + kx][kc * 32 + quad * 8];
      bf16x8 wf = *(const bf16x8*)&Ws[cb][s * 16 + l16][quad * 8];
      if (s % 3 == 0)      ac0 = __builtin_amdgcn_mfma_f32_16x16x32_bf16(af, wf, ac0, 0, 0, 0);
      else if (s % 3 == 1) ac1 = __builtin_amdgcn_mfma_f32_16x16x32_bf16(af, wf, ac1, 0, 0, 0);
      else                 ac2 = __builtin_amdgcn_mfma_f32_16x16x32_bf16(af, wf, ac2, 0, 0, 0);
    }
    if (kc + 1 < NK) stWs((kc + 1) & 1);
    __syncthreads();
  }
  int n = n0 + l16;
  float bv = bias[n];
  constexpr int Wp2 = WW + 2;
#pragma unroll
  for (int r = 0; r < 4; ++r) {
    int pix = m0 + wv * 16 + quad * 4 + r;
    int py = pix >> LGW, px = pix & (WW - 1);
    float v = gelu_exact(ac0[r] + ac1[r] + ac2[r] + bv);
    ((unsigned short*)out)[((long)b * (HH + 2) * Wp2 + (long)(py + 1) * Wp2 + px + 1) * NOUT + n]
        = bfr(v);
  }
}

// ---------------- decoder conv2: wave-per-pixel dual dot (N=2, K=9*C) ----------------
template <int C, int WW, int LGW>
__global__ __launch_bounds__(256) void k_conv2_dot(
    const bf16* __restrict__ mid, const bf16* __restrict__ Wq,
    const float* __restrict__ bias, float* __restrict__ cur) {
  constexpr int HH = WW;
  constexpr int HW = HH * WW;
  constexpr int Wp2 = WW + 2;
  constexpr int CPL = C / 64;  // channels per lane (2 or 1)
  int tid = threadIdx.x, wv = tid >> 6, ln = tid & 63;
  int gw = blockIdx.x * 4 + wv;
  int b = gw >> (2 * LGW);
  int p = gw & (HW - 1);
  int py = p >> LGW, px = p & (WW - 1);
  float r0 = cur[((long)b * 2 + 0) * HW + p];
  float r1 = cur[((long)b * 2 + 1) * HW + p];
  float b0 = bias[0], b1 = bias[1];
  const unsigned short* base = (const unsigned short*)mid +
      ((long)b * (HH + 2) * Wp2 + (long)py * Wp2 + px) * C + ln * CPL;
  const unsigned short* wb = (const unsigned short*)Wq + ln * CPL;
  float s0 = 0.0f, s1 = 0.0f;
#pragma unroll
  for (int t = 0; t < 9; ++t) {
    int dy = t / 3, dx = t - dy * 3;
    const unsigned short* ar = base + ((long)dy * Wp2 + dx) * C;
    const unsigned short* w0r = wb + (long)(t * 16 + 0) * C;
    const unsigned short* w1r = wb + (long)(t * 16 + 1) * C;
    if (CPL == 2) {
      unsigned int a = *(const unsigned int*)ar;
      unsigned int q0 = *(const unsigned int*)w0r;
      unsigned int q1 = *(const unsigned int*)w1r;
      float a0 = shf((unsigned short)a), a1 = shf((unsigned short)(a >> 16));
      s0 += a0 * shf((unsigned short)q0) + a1 * shf((unsigned short)(q0 >> 16));
      s1 += a0 * shf((unsigned short)q1) + a1 * shf((unsigned short)(q1 >> 16));
    } else {
      float a0 = shf(ar[0]);
      s0 += a0 * shf(w0r[0]);
      s1 += a0 * shf(w1r[0]);
    }
  }
#pragma unroll
  for (int o = 32; o; o >>= 1) { s0 += __shfl_xor(s0, o); s1 += __shfl_xor(s1, o); }
  if (ln == 0) {
    cur[((long)b * 2 + 0) * HW + p] = s0 + b0 + r0;
    cur[((long)b * 2 + 1) * HW + p] = s1 + b1 + r1;
  }
}

// ---------------- local correlation from pixel-major bf16 Fp2, bf16 out, stride 64 -------
__global__ void k_corr(const bf16* __restrict__ Fp2, bf16* __restrict__ corrT) {
  __shared__ unsigned short f1r[128];
  int p = blockIdx.x;
  int b = blockIdx.y;
  int t = threadIdx.x;  // 64
  const unsigned short* f1 = (const unsigned short*)Fp2 + ((long)b * 1024 + p) * 128;
  if (t < 16) *(uint4*)&f1r[t * 8] = *(const uint4*)(f1 + t * 8);
  __syncthreads();
  long rowo = ((long)b * 1024 + p) * 64;
  if (t < 49) {
    int dy = t / 7 - 3, dx = t % 7 - 3;
    int h = p >> 5, w = p & 31;
    int p2 = (((h - dy) & 31) << 5) | ((w - dx) & 31);
    const unsigned short* f2 = (const unsigned short*)Fp2 + ((long)(b + 1) * 1024 + p2) * 128;
    float s = 0.0f;
    for (int c = 0; c < 128; c += 8) {
      union { unsigned short u[8]; uint4 v; } av = { .v = *(const uint4*)&f1r[c] };
      union { unsigned short u[8]; uint4 v; } bv = { .v = *(const uint4*)(f2 + c) };
#pragma unroll
      for (int j = 0; j < 8; ++j) s += shf(av.u[j]) * shf(bv.u[j]);
    }
    corrT[rowo + t] = f2bf(s * 0.08838834764831845f);
  } else {
    corrT[rowo + t] = f2bf(0.0f);
  }
}

// ---------------- unified MFMA bf16 GEMM, full-192 superchunk staging ----------------
// KT: compile-time K. BM: 64 (4 M-waves) or 32 (2 M-waves x 2 N-waves).
// AMODE: 0 = fp32 A; 1 = bf16 A; 2 = fused split-K attention merge (K=192);
// 3 = fp32 A with fused LayerNorm (K=192).
// VT: scatter V-region (n>=384) into vt[b][h][48][1024] (BM=64 only).
template <int KT, int BM, int ACT, bool HASRES, int AMODE, int OUTBF, int VT>
__global__ __launch_bounds__(256) void k_gemm_mfma2(
    const void* __restrict__ A, const void* __restrict__ W, long woff,
    const void* __restrict__ bias, long boff, const int* __restrict__ flb,
    const float* __restrict__ res, void* __restrict__ C,
    int M, int N, const int* __restrict__ fl,
    const unsigned short* __restrict__ mop, const float* __restrict__ mml,
    bf16* __restrict__ vtout,
    const void* __restrict__ lnw, long lnwoff,
    const void* __restrict__ lnb, long lnboff) {
  (void)M;
  int isb = *fl;
  constexpr int NKC = ((KT < 192) ? KT : 192) >> 5;  // 32-wide chunks per superchunk
  constexpr int WM = (BM == 64) ? 4 : 2;             // waves along M
  constexpr int NTW = (BM == 64) ? 4 : 2;            // n-tiles per wave
  constexpr int LPR = 256 / BM;                      // lanes per row (AMODE 2/3)
  constexpr int EPL = 192 / LPR;                     // elems per lane (AMODE 2/3)
  __shared__ unsigned short Asm[NKC][BM][40];
  __shared__ unsigned short Wsm[NKC][64][40];
  int tid = threadIdx.x;
  int wv = tid >> 6, ln = tid & 63;
  int quad = ln >> 4, l16 = ln & 15;
  int wm = wv % WM, wn = wv / WM;
  int m0 = blockIdx.y * BM, n0 = blockIdx.x * 64;
  f32x4 acc[NTW] = {};
  for (int s0 = 0; s0 < KT; s0 += 192) {
    if (s0) __syncthreads();
    // ---- stage W (64 cols x NKC*32) ----
    for (int i = tid; i < NKC * 256; i += 256) {
      int c4 = i & 3, r = (i >> 2) & 63, kc = i >> 8;
      long eo = woff + (long)(n0 + r) * KT + s0 + kc * 32 + c4 * 8;
      if (isb) {
        *(uint4*)&Wsm[kc][r][c4 * 8] = *(const uint4*)((const unsigned short*)W + eo);
      } else {
        const float* wp = (const float*)W + eo;
        float4 w0 = *(const float4*)wp;
        float4 w1 = *(const float4*)(wp + 4);
        union { unsigned short u[8]; uint4 v; } pk;
        pk.u[0] = bfr(w0.x); pk.u[1] = bfr(w0.y); pk.u[2] = bfr(w0.z); pk.u[3] = bfr(w0.w);
        pk.u[4] = bfr(w1.x); pk.u[5] = bfr(w1.y); pk.u[6] = bfr(w1.z); pk.u[7] = bfr(w1.w);
        *(uint4*)&Wsm[kc][r][c4 * 8] = pk.v;
      }
    }
    // ---- stage A ----
    if constexpr (AMODE == 1) {
      for (int i = tid; i < NKC * BM * 4; i += 256) {
        int c4 = i & 3, r = (i >> 2) % BM, kc = i / (BM * 4);
        const unsigned short* ap =
            (const unsigned short*)A + (long)(m0 + r) * KT + s0 + kc * 32 + c4 * 8;
        *(uint4*)&Asm[kc][r][c4 * 8] = *(const uint4*)ap;
      }
    } else if constexpr (AMODE == 0) {
      for (int i = tid; i < NKC * BM * 4; i += 256) {
        int c4 = i & 3, r = (i >> 2) % BM, kc = i / (BM * 4);
        const float* ap = (const float*)A + (long)(m0 + r) * KT + s0 + kc * 32 + c4 * 8;
        float4 a0 = *(const float4*)ap;
        float4 a1 = *(const float4*)(ap + 4);
        union { unsigned short u[8]; uint4 v; } pk;
        pk.u[0] = bfr(a0.x); pk.u[1] = bfr(a0.y); pk.u[2] = bfr(a0.z); pk.u[3] = bfr(a0.w);
        pk.u[4] = bfr(a1.x); pk.u[5] = bfr(a1.y); pk.u[6] = bfr(a1.z); pk.u[7] = bfr(a1.w);
        *(uint4*)&Asm[kc][r][c4 * 8] = pk.v;
      }
    } else if constexpr (AMODE == 3) {
      // fused LayerNorm over K=192; LPR lanes per row, EPL contiguous elems each
      int row = tid / LPR, j = tid % LPR;
      const float* xr = (const float*)A + (long)(m0 + row) * 192 + j * EPL;
      float av[EPL];
#pragma unroll
      for (int q4 = 0; q4 < EPL / 4; ++q4) {
        float4 v = *(const float4*)(xr + q4 * 4);
        av[q4 * 4 + 0] = v.x; av[q4 * 4 + 1] = v.y;
        av[q4 * 4 + 2] = v.z; av[q4 * 4 + 3] = v.w;
      }
      float sum = 0.0f;
#pragma unroll
      for (int q = 0; q < EPL; ++q) sum += av[q];
#pragma unroll
      for (int o = 1; o < LPR; o <<= 1) sum += __shfl_xor(sum, o);
      float mean = sum * (1.0f / 192.0f);
      float vs = 0.0f;
#pragma unroll
      for (int q = 0; q < EPL; ++q) { float d = av[q] - mean; vs += d * d; }
#pragma unroll
      for (int o = 1; o < LPR; o <<= 1) vs += __shfl_xor(vs, o);
      float rstd = rsqrtf(vs * (1.0f / 192.0f) + 1e-5f);
#pragma unroll
      for (int g = 0; g < EPL / 8; ++g) {
        int k = j * EPL + g * 8;
        union { unsigned short u[8]; uint4 v; } pk;
#pragma unroll
        for (int e = 0; e < 8; ++e) {
          float gg = ldw(lnw, lnwoff + k + e, isb);
          float bb = ldw(lnb, lnboff + k + e, isb);
          pk.u[e] = bfr((av[g * 8 + e] - mean) * rstd * gg + bb);
        }
        *(uint4*)&Asm[k >> 5][row][k & 31] = pk.v;
      }
    } else {
      // AMODE == 2: fused attention merge (4 split partials, bf16 O, fp32 m/l)
      int row = tid / LPR, j = tid % LPR;
      int m = m0 + row;
      int rr = m & 1023, bb = m >> 10;
#pragma unroll
      for (int g = 0; g < EPL / 8; ++g) {
        int k = j * EPL + g * 8;  // 8-run never crosses a head (48 % 8 == 0)
        int h = k / 48;
        int d0 = k - h * 48;
        long idx[4];
        float ms[4], ls[4];
        float Ms = -1e30f;
#pragma unroll
        for (int s = 0; s < 4; ++s) {
          idx[s] = (((long)s * 2 + bb) * 4 + h) * 1024 + rr;
          ms[s] = mml[idx[s] * 2];
          ls[s] = mml[idx[s] * 2 + 1];
          Ms = fmaxf(Ms, ms[s]);
        }
        float e[4], L = 0.0f;
#pragma unroll
        for (int s = 0; s < 4; ++s) { e[s] = __expf(ms[s] - Ms); L += ls[s] * e[s]; }
        float invL = 1.0f / L;
        union { unsigned short u[8]; uint4 v; } pk;
#pragma unroll
        for (int e2 = 0; e2 < 8; ++e2) {
          float o = 0.0f;
#pragma unroll
          for (int s = 0; s < 4; ++s) o += shf(mop[idx[s] * 48 + d0 + e2]) * e[s];
          pk.u[e2] = bfr(o * invL);
        }
        *(uint4*)&Asm[k >> 5][row][k & 31] = pk.v;
      }
    }
    __syncthreads();
#pragma unroll
    for (int kc = 0; kc < NKC; ++kc) {
      bf16x8 af = *(const bf16x8*)&Asm[kc][wm * 16 + l16][quad * 8];
#pragma unroll
      for (int nt = 0; nt < NTW; ++nt) {
        bf16x8 wf = *(const bf16x8*)&Wsm[kc][(wn * NTW + nt) * 16 + l16][quad * 8];
        acc[nt] = __builtin_amdgcn_mfma_f32_16x16x32_bf16(af, wf, acc[nt], 0, 0, 0);
      }
    }
  }
  int isbb = *flb;
#pragma unroll
  for (int nt = 0; nt < NTW; ++nt) {
    int n = n0 + (wn * NTW + nt) * 16 + l16;
    float bv = ldw(bias, boff + n, isbb);
#pragma unroll
    for (int r = 0; r < 4; ++r) {
      int m = m0 + wm * 16 + quad * 4 + r;
      float v = acc[nt][r] + bv;
      if (HASRES) v += res[(long)m * N + n];
      if (ACT == 1) v = gelu_exact(v);
      if (OUTBF) ((bf16*)C)[(long)m * N + n] = f2bf(v);
      else ((float*)C)[(long)m * N + n] = v;
      if constexpr (VT) {
        if (n >= 384) {
          int hh = (n - 384) / 48, dd = (n - 384) % 48;
          int row = m & 1023, bb = m >> 10;
          vtout[((long)(bb * 4 + hh) * 48 + dd) * 1024 + row] = f2bf(v);
        }
      }
    }
  }
}

// ---------------- head second layer: wave-per-output dot (N=2, K=192) ----------------
__global__ __launch_bounds__(256) void k_head2(const float* __restrict__ A,
                                               const void* __restrict__ W,
                                               const void* __restrict__ bias,
                                               float* __restrict__ C,
                                               const int* __restrict__ fl) {
  int isb = *fl;
  int wv = threadIdx.x >> 6, ln = threadIdx.x & 63;
  int gw = blockIdx.x * 4 + wv;  // 0..4095
  int m = gw >> 1, n = gw & 1;
  const float* a = A + (long)m * 192;
  float s = 0.0f;
#pragma unroll
  for (int q = 0; q < 3; ++q) {
    int j = ln + q * 64;
    s += a[j] * ldw(W, (long)n * 192 + j, isb);
  }
  for (int o = 32; o; o >>= 1) s += __shfl_xor(s, o);
  if (ln == 0) {
    int b = m >> 10, p = m & 1023;
    C[((long)b * 2 + n) * 1024 + p] = s + ldw(bias, n, isb);
  }
}

// ---------------- MFMA flash attention, split-K (4 splits of 4 chunks) -------------------
__global__ __launch_bounds__(256) void k_attn_mfma(const bf16* __restrict__ qkv,
                                                   const bf16* __restrict__ vt,
                                                   unsigned short* __restrict__ opart,
                                                   float* __restrict__ ml) {
  __shared__ unsigned short Qs[64][72];
  __shared__ unsigned short Ks[64][72];
  __shared__ unsigned short Vs[48][72];
  __shared__ unsigned short Ps[64][72];
  int tid = threadIdx.x;
  int wv = tid >> 6, ln = tid & 63, quad = ln >> 4, l16 = ln & 15;
  int h = blockIdx.y, b = blockIdx.z;
  int qt = blockIdx.x >> 2, s = blockIdx.x & 3;
  int q0 = qt * 64;
  const unsigned short* qp = (const unsigned short*)qkv + (long)b * 1024 * 576;
  const unsigned short* vp = (const unsigned short*)vt + ((long)(b * 4 + h) * 48) * 1024;
  for (int i = tid; i < 384; i += 256) {
    int r = i / 6, c = i % 6;
    *(uint4*)&Qs[r][c * 8] = *(const uint4*)(qp + (long)(q0 + r) * 576 + h * 48 + c * 8);
  }
  for (int i = tid; i < 128; i += 256) {
    int r = i >> 1, c = 6 + (i & 1);
    uint4 z = {0, 0, 0, 0};
    *(uint4*)&Qs[r][c * 8] = z;
  }
  float m[4] = {-1e30f, -1e30f, -1e30f, -1e30f};
  float l[4] = {0.0f, 0.0f, 0.0f, 0.0f};
  f32x4 accO[3] = {};
  const float SC = 0.14433756729740643f;
  for (int kc = s * 4; kc < s * 4 + 4; ++kc) {
    int k0 = kc * 64;
    for (int i = tid; i < 384; i += 256) {
      int r = i / 6, c = i % 6;
      *(uint4*)&Ks[r][c * 8] = *(const uint4*)(qp + (long)(k0 + r) * 576 + 192 + h * 48 + c * 8);
    }
    for (int i = tid; i < 128; i += 256) {
      int r = i >> 1, c = 6 + (i & 1);
      uint4 z = {0, 0, 0, 0};
      *(uint4*)&Ks[r][c * 8] = z;
    }
    for (int i = tid; i < 384; i += 256) {
      int d = i >> 3, c = i & 7;
      *(uint4*)&Vs[d][c * 8] = *(const uint4*)(vp + (long)d * 1024 + k0 + c * 8);
    }
    __syncthreads();
    f32x4 accS[4] = {};
    bf16x8 a0 = *(const bf16x8*)&Qs[wv * 16 + l16][quad * 8];
    bf16x8 a1 = *(const bf16x8*)&Qs[wv * 16 + l16][32 + quad * 8];
#pragma unroll
    for (int ct = 0; ct < 4; ++ct) {
      bf16x8 b0 = *(const bf16x8*)&Ks[ct * 16 + l16][quad * 8];
      bf16x8 b1 = *(const bf16x8*)&Ks[ct * 16 + l16][32 + quad * 8];
      accS[ct] = __builtin_amdgcn_mfma_f32_16x16x32_bf16(a0, b0, accS[ct], 0, 0, 0);
      accS[ct] = __builtin_amdgcn_mfma_f32_16x16x32_bf16(a1, b1, accS[ct], 0, 0, 0);
    }
#pragma unroll
    for (int r = 0; r < 4; ++r) {
      float s0 = accS[0][r] * SC, s1 = accS[1][r] * SC;
      float s2 = accS[2][r] * SC, s3 = accS[3][r] * SC;
      float mx = fmaxf(fmaxf(s0, s1), fmaxf(s2, s3));
      for (int o = 8; o; o >>= 1) mx = fmaxf(mx, __shfl_xor(mx, o));
      float mn = fmaxf(m[r], mx);
      float alpha = __expf(m[r] - mn);
      float p0 = __expf(s0 - mn), p1 = __expf(s1 - mn);
      float p2 = __expf(s2 - mn), p3 = __expf(s3 - mn);
      float rs = p0 + p1 + p2 + p3;
      for (int o = 8; o; o >>= 1) rs += __shfl_xor(rs, o);
      m[r] = mn;
      l[r] = l[r] * alpha + rs;
      accO[0][r] *= alpha; accO[1][r] *= alpha; accO[2][r] *= alpha;
      int prow = wv * 16 + quad * 4 + r;
      Ps[prow][l16]      = bfr(p0);
      Ps[prow][16 + l16] = bfr(p1);
      Ps[prow][32 + l16] = bfr(p2);
      Ps[prow][48 + l16] = bfr(p3);
    }
    bf16x8 pf0 = *(const bf16x8*)&Ps[wv * 16 + l16][quad * 8];
    bf16x8 pf1 = *(const bf16x8*)&Ps[wv * 16 + l16][32 + quad * 8];
#pragma unroll
    for (int ct = 0; ct < 3; ++ct) {
      bf16x8 v0 = *(const bf16x8*)&Vs[ct * 16 + l16][quad * 8];
      bf16x8 v1 = *(const bf16x8*)&Vs[ct * 16 + l16][32 + quad * 8];
      accO[ct] = __builtin_amdgcn_mfma_f32_16x16x32_bf16(pf0, v0, accO[ct], 0, 0, 0);
      accO[ct] = __builtin_amdgcn_mfma_f32_16x16x32_bf16(pf1, v1, accO[ct], 0, 0, 0);
    }
    __syncthreads();
  }
  long base = (((long)s * 2 + b) * 4 + h) * 1024;
#pragma unroll
  for (int r = 0; r < 4; ++r) {
    int row = q0 + wv * 16 + quad * 4 + r;
#pragma unroll
    for (int ct = 0; ct < 3; ++ct)
      opart[(base + row) * 48 + ct * 16 + l16] = bfr(accO[ct][r]);
    if (l16 == 0) {
      ml[(base + row) * 2]     = m[r];
      ml[(base + row) * 2 + 1] = l[r];
    }
  }
}

// ---------------- EMA / upsample / out ----------------
__global__ void k_ema(float* __restrict__ x) {
  int i = blockIdx.x * blockDim.x + threadIdx.x;
  if (i < 196608) x[196608 + i] = 0.8f * x[196608 + i] + 0.2f * x[i];
}

__global__ void k_upsample(const float* __restrict__ in, float* __restrict__ out) {
  int i = blockIdx.x * blockDim.x + threadIdx.x;
  if (i >= 2 * 2 * 64 * 64) return;
  int p = i & 4095;
  int bc = i >> 12;
  int oy = p >> 6, ox = p & 63;
  float sx = ox * (31.0f / 63.0f), sy = oy * (31.0f / 63.0f);
  int x0 = (int)sx, y0 = (int)sy;
  int x1 = min(x0 + 1, 31), y1 = min(y0 + 1, 31);
  float wx = sx - x0, wy = sy - y0;
  const float* ic = in + (long)bc * 1024;
  out[i] = ic[y0 * 32 + x0] * (1 - wx) * (1 - wy) + ic[y0 * 32 + x1] * wx * (1 - wy)
         + ic[y1 * 32 + x0] * (1 - wx) * wy      + ic[y1 * 32 + x1] * wx * wy;
}

__global__ void k_out(const float* __restrict__ cur2, void* __restrict__ out,
                      const int* __restrict__ fl) {
  int isb = *fl;
  int i = blockIdx.x * blockDim.x + threadIdx.x;
  if (i < 16384) {
    if (isb) ((bf16*)out)[i] = f2bf(cur2[i]);
    else ((float*)out)[i] = cur2[i];
  }
}

extern "C" void kernel_launch(void* const* d_in, const int* in_sizes, int n_in,
                              void* d_out, int out_size, void* d_ws, size_t ws_size,
                              hipStream_t stream) {
  const void* feats_l1 = d_in[0];
  const void* feats_l2 = d_in[1];
  const void* tok_w = d_in[3];
  const void* tok_b = d_in[4];
  const void* lcm_ln1_w = d_in[5];
  const void* lcm_ln1_b = d_in[6];
  const void* lcm_in_w  = d_in[7];
  const void* lcm_in_b  = d_in[8];
  const void* lcm_out_w = d_in[9];
  const void* lcm_out_b = d_in[10];
  const void* lcm_ln2_w = d_in[11];
  const void* lcm_ln2_b = d_in[12];
  const void* lcm_mlp_w1 = d_in[13];
  const void* lcm_mlp_b1 = d_in[14];
  const void* lcm_mlp_w2 = d_in[15];
  const void* lcm_mlp_b2 = d_in[16];
  const void* gtr_ln1_w = d_in[17];
  const void* gtr_ln1_b = d_in[18];
  const void* gtr_in_w  = d_in[19];
  const void* gtr_in_b  = d_in[20];
  const void* gtr_out_w = d_in[21];
  const void* gtr_out_b = d_in[22];
  const void* gtr_ln2_w = d_in[23];
  const void* gtr_ln2_b = d_in[24];
  const void* gtr_mlp_w1 = d_in[25];
  const void* gtr_mlp_b1 = d_in[26];
  const void* gtr_mlp_w2 = d_in[27];
  const void* gtr_mlp_b2 = d_in[28];
  const void* head_w1 = d_in[29];
  const void* head_b1 = d_in[30];
  const void* head_w2 = d_in[31];
  const void* head_b2 = d_in[32];
  const void* ref1_w1 = d_in[33];
  const void* ref1_b1 = d_in[34];
  const void* ref1_w2 = d_in[35];
  const void* ref1_b2 = d_in[36];
  const void* ref0_w1 = d_in[37];
  const void* ref0_b1 = d_in[38];
  const void* ref0_w2 = d_in[39];
  const void* ref0_b2 = d_in[40];
  (void)ws_size; (void)n_in; (void)in_sizes; (void)out_size;

  // ---- workspace layout (f-eq units; ~16.8 MB) ----
  int* flag = (int*)d_ws;
  int* oneflag = (int*)d_ws + 2;
  float* wsf = (float*)d_ws;
  float* F2   = wsf + 16;             // 393216 (spare; layout stability)
  float* rA   = F2 + 393216;          // 786432 : opart bf16
  float* rX   = rA + 786432;          // 393216 : residual x
  float* rT   = rX + 393216;          // 393216 : head-hidden | mid0packed
  float* rY   = rT + 393216;          // 393216 : mlbuf | mid1packed
  float* big  = rY + 393216;          // 1572864: qkv/vt/hid [0,851968) | Fp2+Fp1 tail
  float* fv   = big + 1572864;        // 4096 (unused)
  float* cur  = fv + 4096;            // 4096
  float* cur2 = cur + 4096;           // 16384
  float* cb1a = cur2 + 16384;         // 128
  float* cb1b = cb1a + 128;           // 16
  float* cb0a = cb1b + 16;            // 64
  float* cb0b = cb0a + 64;            // 16
  bf16* wtok  = (bf16*)(cb0b + 16);   // 12288 shorts
  float* wpk  = cb0b + 16 + 6144;
  bf16* w1p1 = (bf16*)wpk;            // 331776 shorts
  bf16* w1p2 = (bf16*)(wpk + 165888); // 18432 shorts
  bf16* w0p1 = (bf16*)(wpk + 175104); // 92160 shorts
  bf16* w0p2 = (bf16*)(wpk + 221184); // 9216 shorts

  float* x = rX;
  bf16* corrTb = (bf16*)big;
  bf16* qkvbb  = (bf16*)big;
  bf16* vtb    = (bf16*)(big + 655360);
  bf16* hidb   = (bf16*)big;
  unsigned short* opart = (unsigned short*)rA;  // [4][2][4][1024][48] bf16
  float* mlbuf = rY;                            // [4][2][4][1024][2] fp32
  float* headh = rT;
  bf16* mid0p = (bf16*)rT;
  bf16* mid1p = (bf16*)rY;
  bf16* Fp2   = (bf16*)(big + 851968);   // [3][1024][128] = 393216 shorts
  bf16* Fp1   = (bf16*)(big + 1048576);  // [3][4096][64]  = 786432 shorts

  k_detect<<<1, 256, 0, stream>>>((const unsigned short*)feats_l1, flag);
  k_setone<<<1, 1, 0, stream>>>(oneflag);
  k_cvt<<<1, 256, 0, stream>>>(ref1_b1, cb1a, 128, flag);
  k_cvt<<<1, 256, 0, stream>>>(ref1_b2, cb1b, 2, flag);
  k_cvt<<<1, 256, 0, stream>>>(ref0_b1, cb0a, 64, flag);
  k_cvt<<<1, 256, 0, stream>>>(ref0_b2, cb0b, 2, flag);
  k_padtokw<<<48, 256, 0, stream>>>(tok_w, wtok, flag);
  k_packw<<<1296, 256, 0, stream>>>(ref1_w1, w1p1, 128, 128, 258, 128, 288, 331776, flag);
  k_packw<<<72, 256, 0, stream>>>(ref1_w2, w1p2, 2, 128, 128, 16, 128, 18432, flag);
  k_packw<<<360, 256, 0, stream>>>(ref0_w1, w0p1, 64, 64, 130, 64, 160, 92160, flag);
  k_packw<<<36, 256, 0, stream>>>(ref0_w2, w0p2, 2, 64, 64, 16, 64, 9216, flag);
  // pixel-major frames up front (big tail survives qkv/hid which use [0,851968))
  k_trans_feats<<<192, 256, 0, stream>>>(feats_l2, Fp2, 3, 128, 1024, flag);
  k_trans_feats<<<384, 256, 0, stream>>>(feats_l1, Fp1, 3, 64, 4096, flag);

  // ---- tokens: corr (from Fp2) then tokenizer GEMM (BM=32 for occupancy) ----
  k_corr<<<dim3(1024, 2), 64, 0, stream>>>(Fp2, corrTb);
  k_gemm_mfma2<64, 32, 0, false, 1, 0, 0><<<dim3(3, 64), 256, 0, stream>>>(
      corrTb, wtok, 0, tok_b, 192, flag, nullptr, x, 2048, 192, oneflag,
      nullptr, nullptr, nullptr, nullptr, 0, nullptr, 0);

  auto run_block = [&](const void* ln1w, long o1, const void* ln1b, long o2,
                       const void* inw, long o3, const void* inb, long o4,
                       const void* ow, long o5, const void* ob, long o6,
                       const void* ln2w, long o7, const void* ln2b, long o8,
                       const void* w1, long o9, const void* b1, long o10,
                       const void* w2, long o11, const void* b2, long o12) {
    // fused LN1 + qkv GEMM: bf16 out + fused V-transpose scatter
    k_gemm_mfma2<192, 64, 0, false, 3, 1, 1><<<dim3(9, 32), 256, 0, stream>>>(
        x, inw, o3, inb, o4, flag, nullptr, qkvbb, 2048, 576, flag,
        nullptr, nullptr, vtb, ln1w, o1, ln1b, o2);
    k_attn_mfma<<<dim3(64, 4, 2), 256, 0, stream>>>(qkvbb, vtb, opart, mlbuf);
    // out-proj GEMM: fused 4-way split-K merge as A-operand (BM=32)
    k_gemm_mfma2<192, 32, 0, true, 2, 0, 0><<<dim3(3, 64), 256, 0, stream>>>(
        nullptr, ow, o5, ob, o6, flag, x, x, 2048, 192, flag,
        opart, mlbuf, nullptr, nullptr, 0, nullptr, 0);
    // fused LN2 + mlp1 GEMM
    k_gemm_mfma2<192, 64, 1, false, 3, 1, 0><<<dim3(12, 32), 256, 0, stream>>>(
        x, w1, o9, b1, o10, flag, nullptr, hidb, 2048, 768, flag,
        nullptr, nullptr, nullptr, ln2w, o7, ln2b, o8);
    // mlp2 (K=768), BM=32
    k_gemm_mfma2<768, 32, 0, true, 1, 0, 0><<<dim3(3, 64), 256, 0, stream>>>(
        hidb, w2, o11, b2, o12, flag, x, x, 2048, 192, flag,
        nullptr, nullptr, nullptr, nullptr, 0, nullptr, 0);
  };

  for (int i = 0; i < 6; ++i) {
    run_block(lcm_ln1_w, (long)i * 192, lcm_ln1_b, (long)i * 192,
              lcm_in_w, (long)i * 110592, lcm_in_b, (long)i * 576,
              lcm_out_w, (long)i * 36864, lcm_out_b, (long)i * 192,
              lcm_ln2_w, (long)i * 192, lcm_ln2_b, (long)i * 192,
              lcm_mlp_w1, (long)i * 147456, lcm_mlp_b1, (long)i * 768,
              lcm_mlp_w2, (long)i * 147456, lcm_mlp_b2, (long)i * 192);
  }
  k_ema<<<768, 256, 0, stream>>>(x);

  for (int i = 0; i < 2; ++i) {
    run_block(gtr_ln1_w, (long)i * 192, gtr_ln1_b, (long)i * 192,
              gtr_in_w, (long)i * 110592, gtr_in_b, (long)i * 576,
              gtr_out_w, (long)i * 36864, gtr_out_b, (long)i * 192,
              gtr_ln2_w, (long)i * 192, gtr_ln2_b, (long)i * 192,
              gtr_mlp_w1, (long)i * 147456, gtr_mlp_b1, (long)i * 768,
              gtr_mlp_w2, (long)i * 147456, gtr_mlp_b2, (long)i * 192);
  }

  // ---- head -> coarse flow (wave-dot second layer writes [b][2][1024]) ----
  k_gemm_mfma2<192, 32, 1, false, 0, 0, 0><<<dim3(3, 64), 256, 0, stream>>>(
      x, head_w1, 0, head_b1, 0, flag, nullptr, headh, 2048, 192, flag,
      nullptr, nullptr, nullptr, nullptr, 0, nullptr, 0);
  k_head2<<<1024, 256, 0, stream>>>(headh, head_w2, head_b2, cur, flag);

  // ---- decoder prep: zero mid buffers (borders must stay 0) ----
  k_zerosh<<<768, 256, 0, stream>>>((unsigned short*)rT, 196608);

  // ---- decoder level 1 (32x32): C=128, ICP=288, OC=128 ----
  for (int it = 0; it < 4; ++it) {
    k_conv_osa<128, 288, 296, 128, 32, 5><<<dim3(8, 16, 2), 256, 0, stream>>>(
        Fp2, cur, w1p1, cb1a, mid1p);
    k_conv2_dot<128, 32, 5><<<512, 256, 0, stream>>>(mid1p, w1p2, cb1b, cur);
  }
  k_upsample<<<64, 256, 0, stream>>>(cur, cur2);

  // ---- decoder level 0 (64x64): C=64, ICP=160, OC=64 ----
  for (int it = 0; it < 4; ++it) {
    k_conv_osa<64, 160, 168, 64, 64, 6><<<dim3(4, 64, 2), 256, 0, stream>>>(
        Fp1, cur2, w0p1, cb0a, mid0p);
    k_conv2_dot<64, 64, 6><<<2048, 256, 0, stream>>>(mid0p, w0p2, cb0b, cur2);
  }

  k_out<<<64, 256, 0, stream>>>(cur2, d_out, flag);
}

// Round 5
// 1106.074 us; speedup vs baseline: 1.0486x; 1.0486x over previous
//
#include <hip/hip_runtime.h>
#include <hip/hip_bf16.h>

typedef __hip_bfloat16 bf16;
typedef short bf16x8 __attribute__((ext_vector_type(8)));
typedef float f32x4 __attribute__((ext_vector_type(4)));

#define DEV __device__ __forceinline__

DEV float bf2f(bf16 v) { return __bfloat162float(v); }
DEV bf16 f2bf(float v) { return __float2bfloat16(v); }
DEV unsigned short bfr(float f) {
  bf16 h = __float2bfloat16(f);
  return *reinterpret_cast<unsigned short*>(&h);
}
DEV float shf(unsigned short u) {
  unsigned int x = ((unsigned int)u) << 16;
  return *reinterpret_cast<float*>(&x);
}
DEV float gelu_exact(float x) { return 0.5f * x * (1.0f + erff(x * 0.70710678118654752f)); }

DEV float ldw(const void* p, long i, int isb) {
  return isb ? __bfloat162float(((const bf16*)p)[i]) : ((const float*)p)[i];
}

// ---------------- dtype detection + flag constants ----------------
__global__ void k_detect(const unsigned short* __restrict__ u, int* __restrict__ flag) {
  __shared__ int bad;
  if (threadIdx.x == 0) bad = 0;
  __syncthreads();
  for (int i = threadIdx.x; i < 8192; i += 256) {
    int expo = (u[i] >> 7) & 0xFF;
    if (expo >= 138) atomicOr(&bad, 1);
  }
  __syncthreads();
  if (threadIdx.x == 0) *flag = bad ? 0 : 1;
}
__global__ void k_setone(int* p) { *p = 1; }

// ---------------- convert (bf16|fp32) -> fp32 ----------------
__global__ void k_cvt(const void* __restrict__ s, float* __restrict__ d, int n,
                      const int* __restrict__ fl) {
  int isb = *fl;
  int i = blockIdx.x * blockDim.x + threadIdx.x;
  if (i < n) d[i] = ldw(s, i, isb);
}

__global__ void k_zerosh(unsigned short* __restrict__ p, int n8) {
  int i = blockIdx.x * blockDim.x + threadIdx.x;
  if (i < n8) { uint4 z = {0, 0, 0, 0}; *(uint4*)(p + (long)i * 8) = z; }
}

// tokenizer weight [192][49] (at element offset 9408) -> bf16 [192][64] zero-padded
__global__ void k_padtokw(const void* __restrict__ tw, bf16* __restrict__ dst,
                          const int* __restrict__ fl) {
  int isb = *fl;
  int i = blockIdx.x * blockDim.x + threadIdx.x;
  if (i >= 12288) return;
  int n = i >> 6, k = i & 63;
  float v = (k < 49) ? ldw(tw, 9408 + (long)n * 49 + k, isb) : 0.0f;
  dst[i] = f2bf(v);
}

// conv weight pack: dst[s][np][icp] bf16 from src [OC][ICT][9], channel remap feats|warp|flow|0
__global__ void k_packw(const void* __restrict__ src, bf16* __restrict__ dst,
                        int OC, int C, int ICT, int NP, int ICP, int n,
                        const int* __restrict__ fl) {
  int isb = *fl;
  int i = blockIdx.x * blockDim.x + threadIdx.x;
  if (i >= n) return;
  int s = i / (NP * ICP);
  int r = i - s * NP * ICP;
  int oc = r / ICP, icp = r - oc * ICP;
  float v = 0.0f;
  if (oc < OC) {
    int ic = -1;
    if (icp < C) ic = icp;
    else if (icp < 2 * C) ic = icp - C + C + 2;
    else if (icp < 2 * C + 2) ic = icp - 2 * C + C;
    if (ic >= 0 && ic < ICT) v = ldw(src, ((long)oc * ICT + ic) * 9 + s, isb);
  }
  dst[i] = f2bf(v);
}

// feats [F][C][HW] -> pixel-major bf16 [F][HW][C]; one thread per 8-channel group
__global__ void k_trans_feats(const void* __restrict__ in, bf16* __restrict__ Fp,
                              int F, int C, int HW, const int* __restrict__ fl) {
  int isb = *fl;
  int cpg = C >> 3;
  int n = F * HW * cpg;
  int i = blockIdx.x * blockDim.x + threadIdx.x;
  if (i >= n) return;
  int p = i % HW;
  int rem = i / HW;
  int c8 = rem % cpg;
  int f = rem / cpg;
  long base = (long)f * C * HW + (long)(c8 * 8) * HW + p;
  union { unsigned short u[8]; uint4 v; } pk;
#pragma unroll
  for (int j = 0; j < 8; ++j) pk.u[j] = bfr(ldw(in, base + (long)j * HW, isb));
  *(uint4*)((unsigned short*)Fp + ((long)f * HW + p) * C + c8 * 8) = pk.v;
}

// ---------------- decoder conv1: single-wave, barrier-free MFMA 3x3 + fused warp -------
// One wave (64 thr) per block, 16 px x 16 outs. Per-kc register pipeline:
// issue loads(kc+1) -> MFMA(kc) -> store(kc+1). No __syncthreads anywhere (within-wave
// LDS ops are in-order). Grid gives 1024-2048 independent waves -> TLP latency hiding.
template <int C, int ICP, int NP, int WW, int LGW>
__global__ __launch_bounds__(64) void k_conv1w(
    const bf16* __restrict__ Fp, const float* __restrict__ flow,
    const bf16* __restrict__ Wp, const float* __restrict__ bias,
    bf16* __restrict__ out) {
  constexpr int HH = WW, HW = WW * WW;
  constexpr int ACW = 18, APX = 54;
  constexpr int NK = ICP / 32;
  __shared__ unsigned short As[APX][40];
  __shared__ unsigned short Ws[144][40];
  __shared__ int pofs[APX];
  __shared__ int doff[APX][4];
  __shared__ float dwt[APX][4];
  __shared__ float ffl[APX][2];
  int ln = threadIdx.x;
  int quad = ln >> 4, l16 = ln & 15;
  int n0 = blockIdx.x * 16, m0 = blockIdx.y * 16, b = blockIdx.z;
  int py0 = m0 >> LGW, px0 = m0 & (WW - 1);
  const unsigned short* fcur = (const unsigned short*)Fp + (long)b * HW * C;
  const unsigned short* fnxt = (const unsigned short*)Fp + (long)(b + 1) * HW * C;
  const float* fl = flow + (long)b * 2 * HW;
  // ---- per-pixel descriptors (lanes 0..53) ----
  if (ln < APX) {
    int sr = ln / ACW, sc = ln - sr * ACW;
    int py = py0 + sr - 1, px = px0 + sc - 1;
    bool in = py >= 0 && py < HH && px >= 0 && px < WW;
    int p = in ? (py * WW + px) : 0;
    pofs[ln] = in ? p * C : -1;
    float fx = in ? fl[p] : 0.0f, fy = in ? fl[HW + p] : 0.0f;
    float x = fminf(fmaxf((float)px + fx, 0.0f), (float)(WW - 1));
    float y = fminf(fmaxf((float)py + fy, 0.0f), (float)(HH - 1));
    int x0 = (int)floorf(x), y0 = (int)floorf(y);
    int x1 = min(x0 + 1, WW - 1), y1 = min(y0 + 1, HH - 1);
    float wx = x - (float)x0, wy = y - (float)y0;
    dwt[ln][0] = in ? (1 - wx) * (1 - wy) : 0.0f;
    dwt[ln][1] = in ? wx * (1 - wy) : 0.0f;
    dwt[ln][2] = in ? (1 - wx) * wy : 0.0f;
    dwt[ln][3] = in ? wx * wy : 0.0f;
    doff[ln][0] = (y0 * WW + x0) * C; doff[ln][1] = (y0 * WW + x1) * C;
    doff[ln][2] = (y1 * WW + x0) * C; doff[ln][3] = (y1 * WW + x1) * C;
    ffl[ln][0] = in ? fx : 0.0f; ffl[ln][1] = in ? fy : 0.0f;
  }
  uint4 wrg[9];
  uint4 arg[4];
  uint4 qrg[4][4];
  auto ldW = [&](int kc) {
#pragma unroll
    for (int j = 0; j < 9; ++j) {
      int idx = ln + j * 64;
      int r = idx >> 2, c4 = idx & 3;
      int s = r >> 4, nl = r & 15;
      wrg[j] = *(const uint4*)((const unsigned short*)Wp +
               ((long)s * NP + n0 + nl) * ICP + kc * 32 + c4 * 8);
    }
  };
  auto stW = [&]() {
#pragma unroll
    for (int j = 0; j < 9; ++j) {
      int idx = ln + j * 64;
      int r = idx >> 2, c4 = idx & 3;
      *(uint4*)&Ws[r][c4 * 8] = wrg[j];
    }
  };
  auto ldA = [&](int kc) {
    int chb = kc * 32;
    if (chb < C) {
#pragma unroll
      for (int j = 0; j < 4; ++j) {
        int idx = ln + j * 64;
        if (idx < APX * 4) {
          int ap = idx >> 2, c4 = idx & 3;
          int po = pofs[ap];
          uint4 z = {0, 0, 0, 0};
          arg[j] = (po >= 0) ? *(const uint4*)(fcur + po + chb + c4 * 8) : z;
        }
      }
    } else if (chb < 2 * C) {
#pragma unroll
      for (int j = 0; j < 4; ++j) {
        int idx = ln + j * 64;
        if (idx < APX * 4) {
          int ap = idx >> 2, c4 = idx & 3;
          int c = chb - C + c4 * 8;
#pragma unroll
          for (int e = 0; e < 4; ++e)
            qrg[j][e] = *(const uint4*)(fnxt + doff[ap][e] + c);
        }
      }
    }
  };
  auto stA = [&](int kc) {
    int chb = kc * 32;
    if (chb < C) {
#pragma unroll
      for (int j = 0; j < 4; ++j) {
        int idx = ln + j * 64;
        if (idx < APX * 4) {
          int ap = idx >> 2, c4 = idx & 3;
          *(uint4*)&As[ap][c4 * 8] = arg[j];
        }
      }
    } else if (chb < 2 * C) {
#pragma unroll
      for (int j = 0; j < 4; ++j) {
        int idx = ln + j * 64;
        if (idx < APX * 4) {
          int ap = idx >> 2, c4 = idx & 3;
          union { unsigned short u[8]; uint4 v; } a0 = {.v = qrg[j][0]}, a1 = {.v = qrg[j][1]},
                                                  a2 = {.v = qrg[j][2]}, a3 = {.v = qrg[j][3]}, o;
          float q0 = dwt[ap][0], q1 = dwt[ap][1], q2 = dwt[ap][2], q3 = dwt[ap][3];
#pragma unroll
          for (int e = 0; e < 8; ++e)
            o.u[e] = bfr(shf(a0.u[e]) * q0 + shf(a1.u[e]) * q1 +
                         shf(a2.u[e]) * q2 + shf(a3.u[e]) * q3);
          *(uint4*)&As[ap][c4 * 8] = o.v;
        }
      }
    } else {
#pragma unroll
      for (int j = 0; j < 4; ++j) {
        int idx = ln + j * 64;
        if (idx < APX * 4) {
          int ap = idx >> 2, c4 = idx & 3;
          union { unsigned short u[8]; uint4 v; } o = { .v = {0, 0, 0, 0} };
          if (c4 == 0) { o.u[0] = bfr(ffl[ap][0]); o.u[1] = bfr(ffl[ap][1]); }
          *(uint4*)&As[ap][c4 * 8] = o.v;
        }
      }
    }
  };
  f32x4 ac0 = {}, ac1 = {}, ac2 = {};
  auto mm = [&]() {
#pragma unroll
    for (int s = 0; s < 9; ++s) {
      int ky = s / 3, kx = s - ky * 3;
      bf16x8 af = *(const bf16x8*)&As[ky * ACW + l16 + kx][quad * 8];
      bf16x8 wf = *(const bf16x8*)&Ws[s * 16 + l16][quad * 8];
      if (s % 3 == 0)      ac0 = __builtin_amdgcn_mfma_f32_16x16x32_bf16(af, wf, ac0, 0, 0, 0);
      else if (s % 3 == 1) ac1 = __builtin_amdgcn_mfma_f32_16x16x32_bf16(af, wf, ac1, 0, 0, 0);
      else                 ac2 = __builtin_amdgcn_mfma_f32_16x16x32_bf16(af, wf, ac2, 0, 0, 0);
    }
  };
  ldW(0); ldA(0);
  stW(); stA(0);
#pragma unroll
  for (int kc = 0; kc < NK; ++kc) {
    if (kc + 1 < NK) { ldW(kc + 1); ldA(kc + 1); }
    mm();
    if (kc + 1 < NK) { stW(); stA(kc + 1); }
  }
  int n = n0 + l16;
  float bv = bias[n];
  long rowbase = (long)b * (HH + 2) * (WW + 2) + (long)(py0 + 1) * (WW + 2);
#pragma unroll
  for (int r = 0; r < 4; ++r) {
    int px = px0 + quad * 4 + r;
    float v = gelu_exact(ac0[r] + ac1[r] + ac2[r] + bv);
    ((unsigned short*)out)[(rowbase + px + 1) * NP + n] = bfr(v);
  }
}

// ---------------- decoder conv2: wave-per-pixel dual dot (N=2, K=9*C) ----------------
template <int C, int WW, int LGW>
__global__ __launch_bounds__(256) void k_conv2_dot(
    const bf16* __restrict__ mid, const bf16* __restrict__ Wq,
    const float* __restrict__ bias, float* __restrict__ cur) {
  constexpr int HH = WW;
  constexpr int HW = HH * WW;
  constexpr int Wp2 = WW + 2;
  constexpr int CPL = C / 64;  // channels per lane (2 or 1)
  int tid = threadIdx.x, wv = tid >> 6, ln = tid & 63;
  int gw = blockIdx.x * 4 + wv;
  int b = gw >> (2 * LGW);
  int p = gw & (HW - 1);
  int py = p >> LGW, px = p & (WW - 1);
  float r0 = cur[((long)b * 2 + 0) * HW + p];
  float r1 = cur[((long)b * 2 + 1) * HW + p];
  float b0 = bias[0], b1 = bias[1];
  const unsigned short* base = (const unsigned short*)mid +
      ((long)b * (HH + 2) * Wp2 + (long)py * Wp2 + px) * C + ln * CPL;
  const unsigned short* wb = (const unsigned short*)Wq + ln * CPL;
  float s0 = 0.0f, s1 = 0.0f;
#pragma unroll
  for (int t = 0; t < 9; ++t) {
    int dy = t / 3, dx = t - dy * 3;
    const unsigned short* ar = base + ((long)dy * Wp2 + dx) * C;
    const unsigned short* w0r = wb + (long)(t * 16 + 0) * C;
    const unsigned short* w1r = wb + (long)(t * 16 + 1) * C;
    if (CPL == 2) {
      unsigned int a = *(const unsigned int*)ar;
      unsigned int q0 = *(const unsigned int*)w0r;
      unsigned int q1 = *(const unsigned int*)w1r;
      float a0 = shf((unsigned short)a), a1 = shf((unsigned short)(a >> 16));
      s0 += a0 * shf((unsigned short)q0) + a1 * shf((unsigned short)(q0 >> 16));
      s1 += a0 * shf((unsigned short)q1) + a1 * shf((unsigned short)(q1 >> 16));
    } else {
      float a0 = shf(ar[0]);
      s0 += a0 * shf(w0r[0]);
      s1 += a0 * shf(w1r[0]);
    }
  }
#pragma unroll
  for (int o = 32; o; o >>= 1) { s0 += __shfl_xor(s0, o); s1 += __shfl_xor(s1, o); }
  if (ln == 0) {
    cur[((long)b * 2 + 0) * HW + p] = s0 + b0 + r0;
    cur[((long)b * 2 + 1) * HW + p] = s1 + b1 + r1;
  }
}

// ---------------- local correlation from pixel-major bf16 Fp2, bf16 out, stride 64 -------
__global__ void k_corr(const bf16* __restrict__ Fp2, bf16* __restrict__ corrT) {
  __shared__ unsigned short f1r[128];
  int p = blockIdx.x;
  int b = blockIdx.y;
  int t = threadIdx.x;  // 64
  const unsigned short* f1 = (const unsigned short*)Fp2 + ((long)b * 1024 + p) * 128;
  if (t < 16) *(uint4*)&f1r[t * 8] = *(const uint4*)(f1 + t * 8);
  __syncthreads();
  long rowo = ((long)b * 1024 + p) * 64;
  if (t < 49) {
    int dy = t / 7 - 3, dx = t % 7 - 3;
    int h = p >> 5, w = p & 31;
    int p2 = (((h - dy) & 31) << 5) | ((w - dx) & 31);
    const unsigned short* f2 = (const unsigned short*)Fp2 + ((long)(b + 1) * 1024 + p2) * 128;
    float s = 0.0f;
    for (int c = 0; c < 128; c += 8) {
      union { unsigned short u[8]; uint4 v; } av = { .v = *(const uint4*)&f1r[c] };
      union { unsigned short u[8]; uint4 v; } bv = { .v = *(const uint4*)(f2 + c) };
#pragma unroll
      for (int j = 0; j < 8; ++j) s += shf(av.u[j]) * shf(bv.u[j]);
    }
    corrT[rowo + t] = f2bf(s * 0.08838834764831845f);
  } else {
    corrT[rowo + t] = f2bf(0.0f);
  }
}

// ---------------- unified MFMA bf16 GEMM, full-192 superchunk staging ----------------
// KT: compile-time K. BM: 64 (4 M-waves) or 32 (2 M-waves x 2 N-waves).
// AMODE: 0 = fp32 A; 1 = bf16 A; 2 = fused split-K attention merge (K=192);
// 3 = fp32 A with fused LayerNorm (K=192).
// VT: scatter V-region (n>=384) into vt[b][h][48][1024] (BM=64 only).
template <int KT, int BM, int ACT, bool HASRES, int AMODE, int OUTBF, int VT>
__global__ __launch_bounds__(256) void k_gemm_mfma2(
    const void* __restrict__ A, const void* __restrict__ W, long woff,
    const void* __restrict__ bias, long boff, const int* __restrict__ flb,
    const float* __restrict__ res, void* __restrict__ C,
    int M, int N, const int* __restrict__ fl,
    const unsigned short* __restrict__ mop, const float* __restrict__ mml,
    bf16* __restrict__ vtout,
    const void* __restrict__ lnw, long lnwoff,
    const void* __restrict__ lnb, long lnboff) {
  (void)M;
  int isb = *fl;
  constexpr int NKC = ((KT < 192) ? KT : 192) >> 5;  // 32-wide chunks per superchunk
  constexpr int WM = (BM == 64) ? 4 : 2;             // waves along M
  constexpr int NTW = (BM == 64) ? 4 : 2;            // n-tiles per wave
  constexpr int LPR = 256 / BM;                      // lanes per row (AMODE 2/3)
  constexpr int EPL = 192 / LPR;                     // elems per lane (AMODE 2/3)
  __shared__ unsigned short Asm[NKC][BM][40];
  __shared__ unsigned short Wsm[NKC][64][40];
  int tid = threadIdx.x;
  int wv = tid >> 6, ln = tid & 63;
  int quad = ln >> 4, l16 = ln & 15;
  int wm = wv % WM, wn = wv / WM;
  int m0 = blockIdx.y * BM, n0 = blockIdx.x * 64;
  f32x4 acc[NTW] = {};
  for (int s0 = 0; s0 < KT; s0 += 192) {
    if (s0) __syncthreads();
    // ---- stage W (64 cols x NKC*32) ----
    for (int i = tid; i < NKC * 256; i += 256) {
      int c4 = i & 3, r = (i >> 2) & 63, kc = i >> 8;
      long eo = woff + (long)(n0 + r) * KT + s0 + kc * 32 + c4 * 8;
      if (isb) {
        *(uint4*)&Wsm[kc][r][c4 * 8] = *(const uint4*)((const unsigned short*)W + eo);
      } else {
        const float* wp = (const float*)W + eo;
        float4 w0 = *(const float4*)wp;
        float4 w1 = *(const float4*)(wp + 4);
        union { unsigned short u[8]; uint4 v; } pk;
        pk.u[0] = bfr(w0.x); pk.u[1] = bfr(w0.y); pk.u[2] = bfr(w0.z); pk.u[3] = bfr(w0.w);
        pk.u[4] = bfr(w1.x); pk.u[5] = bfr(w1.y); pk.u[6] = bfr(w1.z); pk.u[7] = bfr(w1.w);
        *(uint4*)&Wsm[kc][r][c4 * 8] = pk.v;
      }
    }
    // ---- stage A ----
    if constexpr (AMODE == 1) {
      for (int i = tid; i < NKC * BM * 4; i += 256) {
        int c4 = i & 3, r = (i >> 2) % BM, kc = i / (BM * 4);
        const unsigned short* ap =
            (const unsigned short*)A + (long)(m0 + r) * KT + s0 + kc * 32 + c4 * 8;
        *(uint4*)&Asm[kc][r][c4 * 8] = *(const uint4*)ap;
      }
    } else if constexpr (AMODE == 0) {
      for (int i = tid; i < NKC * BM * 4; i += 256) {
        int c4 = i & 3, r = (i >> 2) % BM, kc = i / (BM * 4);
        const float* ap = (const float*)A + (long)(m0 + r) * KT + s0 + kc * 32 + c4 * 8;
        float4 a0 = *(const float4*)ap;
        float4 a1 = *(const float4*)(ap + 4);
        union { unsigned short u[8]; uint4 v; } pk;
        pk.u[0] = bfr(a0.x); pk.u[1] = bfr(a0.y); pk.u[2] = bfr(a0.z); pk.u[3] = bfr(a0.w);
        pk.u[4] = bfr(a1.x); pk.u[5] = bfr(a1.y); pk.u[6] = bfr(a1.z); pk.u[7] = bfr(a1.w);
        *(uint4*)&Asm[kc][r][c4 * 8] = pk.v;
      }
    } else if constexpr (AMODE == 3) {
      // fused LayerNorm over K=192; LPR lanes per row, EPL contiguous elems each
      int row = tid / LPR, j = tid % LPR;
      const float* xr = (const float*)A + (long)(m0 + row) * 192 + j * EPL;
      float av[EPL];
#pragma unroll
      for (int q4 = 0; q4 < EPL / 4; ++q4) {
        float4 v = *(const float4*)(xr + q4 * 4);
        av[q4 * 4 + 0] = v.x; av[q4 * 4 + 1] = v.y;
        av[q4 * 4 + 2] = v.z; av[q4 * 4 + 3] = v.w;
      }
      float sum = 0.0f;
#pragma unroll
      for (int q = 0; q < EPL; ++q) sum += av[q];
#pragma unroll
      for (int o = 1; o < LPR; o <<= 1) sum += __shfl_xor(sum, o);
      float mean = sum * (1.0f / 192.0f);
      float vs = 0.0f;
#pragma unroll
      for (int q = 0; q < EPL; ++q) { float d = av[q] - mean; vs += d * d; }
#pragma unroll
      for (int o = 1; o < LPR; o <<= 1) vs += __shfl_xor(vs, o);
      float rstd = rsqrtf(vs * (1.0f / 192.0f) + 1e-5f);
#pragma unroll
      for (int g = 0; g < EPL / 8; ++g) {
        int k = j * EPL + g * 8;
        union { unsigned short u[8]; uint4 v; } pk;
#pragma unroll
        for (int e = 0; e < 8; ++e) {
          float gg = ldw(lnw, lnwoff + k + e, isb);
          float bb = ldw(lnb, lnboff + k + e, isb);
          pk.u[e] = bfr((av[g * 8 + e] - mean) * rstd * gg + bb);
        }
        *(uint4*)&Asm[k >> 5][row][k & 31] = pk.v;
      }
    } else {
      // AMODE == 2: fused attention merge (4 split partials, bf16 O, fp32 m/l)
      int row = tid / LPR, j = tid % LPR;
      int m = m0 + row;
      int rr = m & 1023, bb = m >> 10;
#pragma unroll
      for (int g = 0; g < EPL / 8; ++g) {
        int k = j * EPL + g * 8;  // 8-run never crosses a head (48 % 8 == 0)
        int h = k / 48;
        int d0 = k - h * 48;
        long idx[4];
        float ms[4], ls[4];
        float Ms = -1e30f;
#pragma unroll
        for (int s = 0; s < 4; ++s) {
          idx[s] = (((long)s * 2 + bb) * 4 + h) * 1024 + rr;
          ms[s] = mml[idx[s] * 2];
          ls[s] = mml[idx[s] * 2 + 1];
          Ms = fmaxf(Ms, ms[s]);
        }
        float e[4], L = 0.0f;
#pragma unroll
        for (int s = 0; s < 4; ++s) { e[s] = __expf(ms[s] - Ms); L += ls[s] * e[s]; }
        float invL = 1.0f / L;
        union { unsigned short u[8]; uint4 v; } pk;
#pragma unroll
        for (int e2 = 0; e2 < 8; ++e2) {
          float o = 0.0f;
#pragma unroll
          for (int s = 0; s < 4; ++s) o += shf(mop[idx[s] * 48 + d0 + e2]) * e[s];
          pk.u[e2] = bfr(o * invL);
        }
        *(uint4*)&Asm[k >> 5][row][k & 31] = pk.v;
      }
    }
    __syncthreads();
#pragma unroll
    for (int kc = 0; kc < NKC; ++kc) {
      bf16x8 af = *(const bf16x8*)&Asm[kc][wm * 16 + l16][quad * 8];
#pragma unroll
      for (int nt = 0; nt < NTW; ++nt) {
        bf16x8 wf = *(const bf16x8*)&Wsm[kc][(wn * NTW + nt) * 16 + l16][quad * 8];
        acc[nt] = __builtin_amdgcn_mfma_f32_16x16x32_bf16(af, wf, acc[nt], 0, 0, 0);
      }
    }
  }
  int isbb = *flb;
#pragma unroll
  for (int nt = 0; nt < NTW; ++nt) {
    int n = n0 + (wn * NTW + nt) * 16 + l16;
    float bv = ldw(bias, boff + n, isbb);
#pragma unroll
    for (int r = 0; r < 4; ++r) {
      int m = m0 + wm * 16 + quad * 4 + r;
      float v = acc[nt][r] + bv;
      if (HASRES) v += res[(long)m * N + n];
      if (ACT == 1) v = gelu_exact(v);
      if (OUTBF) ((bf16*)C)[(long)m * N + n] = f2bf(v);
      else ((float*)C)[(long)m * N + n] = v;
      if constexpr (VT) {
        if (n >= 384) {
          int hh = (n - 384) / 48, dd = (n - 384) % 48;
          int row = m & 1023, bb = m >> 10;
          vtout[((long)(bb * 4 + hh) * 48 + dd) * 1024 + row] = f2bf(v);
        }
      }
    }
  }
}

// ---------------- head second layer: wave-per-output dot (N=2, K=192) ----------------
__global__ __launch_bounds__(256) void k_head2(const float* __restrict__ A,
                                               const void* __restrict__ W,
                                               const void* __restrict__ bias,
                                               float* __restrict__ C,
                                               const int* __restrict__ fl) {
  int isb = *fl;
  int wv = threadIdx.x >> 6, ln = threadIdx.x & 63;
  int gw = blockIdx.x * 4 + wv;  // 0..4095
  int m = gw >> 1, n = gw & 1;
  const float* a = A + (long)m * 192;
  float s = 0.0f;
#pragma unroll
  for (int q = 0; q < 3; ++q) {
    int j = ln + q * 64;
    s += a[j] * ldw(W, (long)n * 192 + j, isb);
  }
  for (int o = 32; o; o >>= 1) s += __shfl_xor(s, o);
  if (ln == 0) {
    int b = m >> 10, p = m & 1023;
    C[((long)b * 2 + n) * 1024 + p] = s + ldw(bias, n, isb);
  }
}

// ---------------- MFMA flash attention, split-K (4 splits of 4 chunks) -------------------
__global__ __launch_bounds__(256) void k_attn_mfma(const bf16* __restrict__ qkv,
                                                   const bf16* __restrict__ vt,
                                                   unsigned short* __restrict__ opart,
                                                   float* __restrict__ ml) {
  __shared__ unsigned short Qs[64][72];
  __shared__ unsigned short Ks[64][72];
  __shared__ unsigned short Vs[48][72];
  __shared__ unsigned short Ps[64][72];
  int tid = threadIdx.x;
  int wv = tid >> 6, ln = tid & 63, quad = ln >> 4, l16 = ln & 15;
  int h = blockIdx.y, b = blockIdx.z;
  int qt = blockIdx.x >> 2, s = blockIdx.x & 3;
  int q0 = qt * 64;
  const unsigned short* qp = (const unsigned short*)qkv + (long)b * 1024 * 576;
  const unsigned short* vp = (const unsigned short*)vt + ((long)(b * 4 + h) * 48) * 1024;
  for (int i = tid; i < 384; i += 256) {
    int r = i / 6, c = i % 6;
    *(uint4*)&Qs[r][c * 8] = *(const uint4*)(qp + (long)(q0 + r) * 576 + h * 48 + c * 8);
  }
  for (int i = tid; i < 128; i += 256) {
    int r = i >> 1, c = 6 + (i & 1);
    uint4 z = {0, 0, 0, 0};
    *(uint4*)&Qs[r][c * 8] = z;
  }
  float m[4] = {-1e30f, -1e30f, -1e30f, -1e30f};
  float l[4] = {0.0f, 0.0f, 0.0f, 0.0f};
  f32x4 accO[3] = {};
  const float SC = 0.14433756729740643f;
  for (int kc = s * 4; kc < s * 4 + 4; ++kc) {
    int k0 = kc * 64;
    for (int i = tid; i < 384; i += 256) {
      int r = i / 6, c = i % 6;
      *(uint4*)&Ks[r][c * 8] = *(const uint4*)(qp + (long)(k0 + r) * 576 + 192 + h * 48 + c * 8);
    }
    for (int i = tid; i < 128; i += 256) {
      int r = i >> 1, c = 6 + (i & 1);
      uint4 z = {0, 0, 0, 0};
      *(uint4*)&Ks[r][c * 8] = z;
    }
    for (int i = tid; i < 384; i += 256) {
      int d = i >> 3, c = i & 7;
      *(uint4*)&Vs[d][c * 8] = *(const uint4*)(vp + (long)d * 1024 + k0 + c * 8);
    }
    __syncthreads();
    f32x4 accS[4] = {};
    bf16x8 a0 = *(const bf16x8*)&Qs[wv * 16 + l16][quad * 8];
    bf16x8 a1 = *(const bf16x8*)&Qs[wv * 16 + l16][32 + quad * 8];
#pragma unroll
    for (int ct = 0; ct < 4; ++ct) {
      bf16x8 b0 = *(const bf16x8*)&Ks[ct * 16 + l16][quad * 8];
      bf16x8 b1 = *(const bf16x8*)&Ks[ct * 16 + l16][32 + quad * 8];
      accS[ct] = __builtin_amdgcn_mfma_f32_16x16x32_bf16(a0, b0, accS[ct], 0, 0, 0);
      accS[ct] = __builtin_amdgcn_mfma_f32_16x16x32_bf16(a1, b1, accS[ct], 0, 0, 0);
    }
#pragma unroll
    for (int r = 0; r < 4; ++r) {
      float s0 = accS[0][r] * SC, s1 = accS[1][r] * SC;
      float s2 = accS[2][r] * SC, s3 = accS[3][r] * SC;
      float mx = fmaxf(fmaxf(s0, s1), fmaxf(s2, s3));
      for (int o = 8; o; o >>= 1) mx = fmaxf(mx, __shfl_xor(mx, o));
      float mn = fmaxf(m[r], mx);
      float alpha = __expf(m[r] - mn);
      float p0 = __expf(s0 - mn), p1 = __expf(s1 - mn);
      float p2 = __expf(s2 - mn), p3 = __expf(s3 - mn);
      float rs = p0 + p1 + p2 + p3;
      for (int o = 8; o; o >>= 1) rs += __shfl_xor(rs, o);
      m[r] = mn;
      l[r] = l[r] * alpha + rs;
      accO[0][r] *= alpha; accO[1][r] *= alpha; accO[2][r] *= alpha;
      int prow = wv * 16 + quad * 4 + r;
      Ps[prow][l16]      = bfr(p0);
      Ps[prow][16 + l16] = bfr(p1);
      Ps[prow][32 + l16] = bfr(p2);
      Ps[prow][48 + l16] = bfr(p3);
    }
    bf16x8 pf0 = *(const bf16x8*)&Ps[wv * 16 + l16][quad * 8];
    bf16x8 pf1 = *(const bf16x8*)&Ps[wv * 16 + l16][32 + quad * 8];
#pragma unroll
    for (int ct = 0; ct < 3; ++ct) {
      bf16x8 v0 = *(const bf16x8*)&Vs[ct * 16 + l16][quad * 8];
      bf16x8 v1 = *(const bf16x8*)&Vs[ct * 16 + l16][32 + quad * 8];
      accO[ct] = __builtin_amdgcn_mfma_f32_16x16x32_bf16(pf0, v0, accO[ct], 0, 0, 0);
      accO[ct] = __builtin_amdgcn_mfma_f32_16x16x32_bf16(pf1, v1, accO[ct], 0, 0, 0);
    }
    __syncthreads();
  }
  long base = (((long)s * 2 + b) * 4 + h) * 1024;
#pragma unroll
  for (int r = 0; r < 4; ++r) {
    int row = q0 + wv * 16 + quad * 4 + r;
#pragma unroll
    for (int ct = 0; ct < 3; ++ct)
      opart[(base + row) * 48 + ct * 16 + l16] = bfr(accO[ct][r]);
    if (l16 == 0) {
      ml[(base + row) * 2]     = m[r];
      ml[(base + row) * 2 + 1] = l[r];
    }
  }
}

// ---------------- EMA / upsample / out ----------------
__global__ void k_ema(float* __restrict__ x) {
  int i = blockIdx.x * blockDim.x + threadIdx.x;
  if (i < 196608) x[196608 + i] = 0.8f * x[196608 + i] + 0.2f * x[i];
}

__global__ void k_upsample(const float* __restrict__ in, float* __restrict__ out) {
  int i = blockIdx.x * blockDim.x + threadIdx.x;
  if (i >= 2 * 2 * 64 * 64) return;
  int p = i & 4095;
  int bc = i >> 12;
  int oy = p >> 6, ox = p & 63;
  float sx = ox * (31.0f / 63.0f), sy = oy * (31.0f / 63.0f);
  int x0 = (int)sx, y0 = (int)sy;
  int x1 = min(x0 + 1, 31), y1 = min(y0 + 1, 31);
  float wx = sx - x0, wy = sy - y0;
  const float* ic = in + (long)bc * 1024;
  out[i] = ic[y0 * 32 + x0] * (1 - wx) * (1 - wy) + ic[y0 * 32 + x1] * wx * (1 - wy)
         + ic[y1 * 32 + x0] * (1 - wx) * wy      + ic[y1 * 32 + x1] * wx * wy;
}

__global__ void k_out(const float* __restrict__ cur2, void* __restrict__ out,
                      const int* __restrict__ fl) {
  int isb = *fl;
  int i = blockIdx.x * blockDim.x + threadIdx.x;
  if (i < 16384) {
    if (isb) ((bf16*)out)[i] = f2bf(cur2[i]);
    else ((float*)out)[i] = cur2[i];
  }
}

extern "C" void kernel_launch(void* const* d_in, const int* in_sizes, int n_in,
                              void* d_out, int out_size, void* d_ws, size_t ws_size,
                              hipStream_t stream) {
  const void* feats_l1 = d_in[0];
  const void* feats_l2 = d_in[1];
  const void* tok_w = d_in[3];
  const void* tok_b = d_in[4];
  const void* lcm_ln1_w = d_in[5];
  const void* lcm_ln1_b = d_in[6];
  const void* lcm_in_w  = d_in[7];
  const void* lcm_in_b  = d_in[8];
  const void* lcm_out_w = d_in[9];
  const void* lcm_out_b = d_in[10];
  const void* lcm_ln2_w = d_in[11];
  const void* lcm_ln2_b = d_in[12];
  const void* lcm_mlp_w1 = d_in[13];
  const void* lcm_mlp_b1 = d_in[14];
  const void* lcm_mlp_w2 = d_in[15];
  const void* lcm_mlp_b2 = d_in[16];
  const void* gtr_ln1_w = d_in[17];
  const void* gtr_ln1_b = d_in[18];
  const void* gtr_in_w  = d_in[19];
  const void* gtr_in_b  = d_in[20];
  const void* gtr_out_w = d_in[21];
  const void* gtr_out_b = d_in[22];
  const void* gtr_ln2_w = d_in[23];
  const void* gtr_ln2_b = d_in[24];
  const void* gtr_mlp_w1 = d_in[25];
  const void* gtr_mlp_b1 = d_in[26];
  const void* gtr_mlp_w2 = d_in[27];
  const void* gtr_mlp_b2 = d_in[28];
  const void* head_w1 = d_in[29];
  const void* head_b1 = d_in[30];
  const void* head_w2 = d_in[31];
  const void* head_b2 = d_in[32];
  const void* ref1_w1 = d_in[33];
  const void* ref1_b1 = d_in[34];
  const void* ref1_w2 = d_in[35];
  const void* ref1_b2 = d_in[36];
  const void* ref0_w1 = d_in[37];
  const void* ref0_b1 = d_in[38];
  const void* ref0_w2 = d_in[39];
  const void* ref0_b2 = d_in[40];
  (void)ws_size; (void)n_in; (void)in_sizes; (void)out_size;

  // ---- workspace layout (f-eq units; ~16.8 MB) ----
  int* flag = (int*)d_ws;
  int* oneflag = (int*)d_ws + 2;
  float* wsf = (float*)d_ws;
  float* F2   = wsf + 16;             // 393216 (spare; layout stability)
  float* rA   = F2 + 393216;          // 786432 : opart bf16
  float* rX   = rA + 786432;          // 393216 : residual x
  float* rT   = rX + 393216;          // 393216 : head-hidden | mid0packed
  float* rY   = rT + 393216;          // 393216 : mlbuf | mid1packed
  float* big  = rY + 393216;          // 1572864: qkv/vt/hid [0,851968) | Fp2+Fp1 tail
  float* fv   = big + 1572864;        // 4096 (unused)
  float* cur  = fv + 4096;            // 4096
  float* cur2 = cur + 4096;           // 16384
  float* cb1a = cur2 + 16384;         // 128
  float* cb1b = cb1a + 128;           // 16
  float* cb0a = cb1b + 16;            // 64
  float* cb0b = cb0a + 64;            // 16
  bf16* wtok  = (bf16*)(cb0b + 16);   // 12288 shorts
  float* wpk  = cb0b + 16 + 6144;
  bf16* w1p1 = (bf16*)wpk;            // 331776 shorts
  bf16* w1p2 = (bf16*)(wpk + 165888); // 18432 shorts
  bf16* w0p1 = (bf16*)(wpk + 175104); // 92160 shorts
  bf16* w0p2 = (bf16*)(wpk + 221184); // 9216 shorts

  float* x = rX;
  bf16* corrTb = (bf16*)big;
  bf16* qkvbb  = (bf16*)big;
  bf16* vtb    = (bf16*)(big + 655360);
  bf16* hidb   = (bf16*)big;
  unsigned short* opart = (unsigned short*)rA;  // [4][2][4][1024][48] bf16
  float* mlbuf = rY;                            // [4][2][4][1024][2] fp32
  float* headh = rT;
  bf16* mid0p = (bf16*)rT;
  bf16* mid1p = (bf16*)rY;
  bf16* Fp2   = (bf16*)(big + 851968);   // [3][1024][128] = 393216 shorts
  bf16* Fp1   = (bf16*)(big + 1048576);  // [3][4096][64]  = 786432 shorts

  k_detect<<<1, 256, 0, stream>>>((const unsigned short*)feats_l1, flag);
  k_setone<<<1, 1, 0, stream>>>(oneflag);
  k_cvt<<<1, 256, 0, stream>>>(ref1_b1, cb1a, 128, flag);
  k_cvt<<<1, 256, 0, stream>>>(ref1_b2, cb1b, 2, flag);
  k_cvt<<<1, 256, 0, stream>>>(ref0_b1, cb0a, 64, flag);
  k_cvt<<<1, 256, 0, stream>>>(ref0_b2, cb0b, 2, flag);
  k_padtokw<<<48, 256, 0, stream>>>(tok_w, wtok, flag);
  k_packw<<<1296, 256, 0, stream>>>(ref1_w1, w1p1, 128, 128, 258, 128, 288, 331776, flag);
  k_packw<<<72, 256, 0, stream>>>(ref1_w2, w1p2, 2, 128, 128, 16, 128, 18432, flag);
  k_packw<<<360, 256, 0, stream>>>(ref0_w1, w0p1, 64, 64, 130, 64, 160, 92160, flag);
  k_packw<<<36, 256, 0, stream>>>(ref0_w2, w0p2, 2, 64, 64, 16, 64, 9216, flag);
  // pixel-major frames up front (big tail survives qkv/hid which use [0,851968))
  k_trans_feats<<<192, 256, 0, stream>>>(feats_l2, Fp2, 3, 128, 1024, flag);
  k_trans_feats<<<384, 256, 0, stream>>>(feats_l1, Fp1, 3, 64, 4096, flag);

  // ---- tokens: corr (from Fp2) then tokenizer GEMM (BM=32 for occupancy) ----
  k_corr<<<dim3(1024, 2), 64, 0, stream>>>(Fp2, corrTb);
  k_gemm_mfma2<64, 32, 0, false, 1, 0, 0><<<dim3(3, 64), 256, 0, stream>>>(
      corrTb, wtok, 0, tok_b, 192, flag, nullptr, x, 2048, 192, oneflag,
      nullptr, nullptr, nullptr, nullptr, 0, nullptr, 0);

  auto run_block = [&](const void* ln1w, long o1, const void* ln1b, long o2,
                       const void* inw, long o3, const void* inb, long o4,
                       const void* ow, long o5, const void* ob, long o6,
                       const void* ln2w, long o7, const void* ln2b, long o8,
                       const void* w1, long o9, const void* b1, long o10,
                       const void* w2, long o11, const void* b2, long o12) {
    // fused LN1 + qkv GEMM: bf16 out + fused V-transpose scatter
    k_gemm_mfma2<192, 64, 0, false, 3, 1, 1><<<dim3(9, 32), 256, 0, stream>>>(
        x, inw, o3, inb, o4, flag, nullptr, qkvbb, 2048, 576, flag,
        nullptr, nullptr, vtb, ln1w, o1, ln1b, o2);
    k_attn_mfma<<<dim3(64, 4, 2), 256, 0, stream>>>(qkvbb, vtb, opart, mlbuf);
    // out-proj GEMM: fused 4-way split-K merge as A-operand (BM=32)
    k_gemm_mfma2<192, 32, 0, true, 2, 0, 0><<<dim3(3, 64), 256, 0, stream>>>(
        nullptr, ow, o5, ob, o6, flag, x, x, 2048, 192, flag,
        opart, mlbuf, nullptr, nullptr, 0, nullptr, 0);
    // fused LN2 + mlp1 GEMM
    k_gemm_mfma2<192, 64, 1, false, 3, 1, 0><<<dim3(12, 32), 256, 0, stream>>>(
        x, w1, o9, b1, o10, flag, nullptr, hidb, 2048, 768, flag,
        nullptr, nullptr, nullptr, ln2w, o7, ln2b, o8);
    // mlp2 (K=768), BM=32
    k_gemm_mfma2<768, 32, 0, true, 1, 0, 0><<<dim3(3, 64), 256, 0, stream>>>(
        hidb, w2, o11, b2, o12, flag, x, x, 2048, 192, flag,
        nullptr, nullptr, nullptr, nullptr, 0, nullptr, 0);
  };

  for (int i = 0; i < 6; ++i) {
    run_block(lcm_ln1_w, (long)i * 192, lcm_ln1_b, (long)i * 192,
              lcm_in_w, (long)i * 110592, lcm_in_b, (long)i * 576,
              lcm_out_w, (long)i * 36864, lcm_out_b, (long)i * 192,
              lcm_ln2_w, (long)i * 192, lcm_ln2_b, (long)i * 192,
              lcm_mlp_w1, (long)i * 147456, lcm_mlp_b1, (long)i * 768,
              lcm_mlp_w2, (long)i * 147456, lcm_mlp_b2, (long)i * 192);
  }
  k_ema<<<768, 256, 0, stream>>>(x);

  for (int i = 0; i < 2; ++i) {
    run_block(gtr_ln1_w, (long)i * 192, gtr_ln1_b, (long)i * 192,
              gtr_in_w, (long)i * 110592, gtr_in_b, (long)i * 576,
              gtr_out_w, (long)i * 36864, gtr_out_b, (long)i * 192,
              gtr_ln2_w, (long)i * 192, gtr_ln2_b, (long)i * 192,
              gtr_mlp_w1, (long)i * 147456, gtr_mlp_b1, (long)i * 768,
              gtr_mlp_w2, (long)i * 147456, gtr_mlp_b2, (long)i * 192);
  }

  // ---- head -> coarse flow (wave-dot second layer writes [b][2][1024]) ----
  k_gemm_mfma2<192, 32, 1, false, 0, 0, 0><<<dim3(3, 64), 256, 0, stream>>>(
      x, head_w1, 0, head_b1, 0, flag, nullptr, headh, 2048, 192, flag,
      nullptr, nullptr, nullptr, nullptr, 0, nullptr, 0);
  k_head2<<<1024, 256, 0, stream>>>(headh, head_w2, head_b2, cur, flag);

  // ---- decoder prep: zero mid buffers (borders must stay 0) ----
  k_zerosh<<<768, 256, 0, stream>>>((unsigned short*)rT, 196608);

  // ---- decoder level 1 (32x32): C=128, ICP=288, OC=128 ----
  for (int it = 0; it < 4; ++it) {
    k_conv1w<128, 288, 128, 32, 5><<<dim3(8, 64, 2), 64, 0, stream>>>(
        Fp2, cur, w1p1, cb1a, mid1p);
    k_conv2_dot<128, 32, 5><<<512, 256, 0, stream>>>(mid1p, w1p2, cb1b, cur);
  }
  k_upsample<<<64, 256, 0, stream>>>(cur, cur2);

  // ---- decoder level 0 (64x64): C=64, ICP=160, OC=64 ----
  for (int it = 0; it < 4; ++it) {
    k_conv1w<64, 160, 64, 64, 6><<<dim3(4, 256, 2), 64, 0, stream>>>(
        Fp1, cur2, w0p1, cb0a, mid0p);
    k_conv2_dot<64, 64, 6><<<2048, 256, 0, stream>>>(mid0p, w0p2, cb0b, cur2);
  }

  k_out<<<64, 256, 0, stream>>>(cur2, d_out, flag);
}

// Round 6
// 994.520 us; speedup vs baseline: 1.1662x; 1.1122x over previous
//
#include <hip/hip_runtime.h>
#include <hip/hip_bf16.h>

typedef __hip_bfloat16 bf16;
typedef short bf16x8 __attribute__((ext_vector_type(8)));
typedef float f32x4 __attribute__((ext_vector_type(4)));

#define DEV __device__ __forceinline__

DEV float bf2f(bf16 v) { return __bfloat162float(v); }
DEV bf16 f2bf(float v) { return __float2bfloat16(v); }
DEV unsigned short bfr(float f) {
  bf16 h = __float2bfloat16(f);
  return *reinterpret_cast<unsigned short*>(&h);
}
DEV float shf(unsigned short u) {
  unsigned int x = ((unsigned int)u) << 16;
  return *reinterpret_cast<float*>(&x);
}
DEV float gelu_exact(float x) { return 0.5f * x * (1.0f + erff(x * 0.70710678118654752f)); }

DEV float ldw(const void* p, long i, int isb) {
  return isb ? __bfloat162float(((const bf16*)p)[i]) : ((const float*)p)[i];
}

// ---------------- dtype detection + flag constants ----------------
__global__ void k_detect(const unsigned short* __restrict__ u, int* __restrict__ flag) {
  __shared__ int bad;
  if (threadIdx.x == 0) bad = 0;
  __syncthreads();
  for (int i = threadIdx.x; i < 8192; i += 256) {
    int expo = (u[i] >> 7) & 0xFF;
    if (expo >= 138) atomicOr(&bad, 1);
  }
  __syncthreads();
  if (threadIdx.x == 0) *flag = bad ? 0 : 1;
}
__global__ void k_setone(int* p) { *p = 1; }

// ---------------- convert (bf16|fp32) -> fp32 ----------------
__global__ void k_cvt(const void* __restrict__ s, float* __restrict__ d, int n,
                      const int* __restrict__ fl) {
  int isb = *fl;
  int i = blockIdx.x * blockDim.x + threadIdx.x;
  if (i < n) d[i] = ldw(s, i, isb);
}

__global__ void k_zerosh(unsigned short* __restrict__ p, int n8) {
  int i = blockIdx.x * blockDim.x + threadIdx.x;
  if (i < n8) { uint4 z = {0, 0, 0, 0}; *(uint4*)(p + (long)i * 8) = z; }
}

// tokenizer weight [192][49] (at element offset 9408) -> bf16 [192][64] zero-padded
__global__ void k_padtokw(const void* __restrict__ tw, bf16* __restrict__ dst,
                          const int* __restrict__ fl) {
  int isb = *fl;
  int i = blockIdx.x * blockDim.x + threadIdx.x;
  if (i >= 12288) return;
  int n = i >> 6, k = i & 63;
  float v = (k < 49) ? ldw(tw, 9408 + (long)n * 49 + k, isb) : 0.0f;
  dst[i] = f2bf(v);
}

// conv weight pack: dst[s][np][icp] bf16 from src [OC][ICT][9], channel remap feats|warp|flow|0
__global__ void k_packw(const void* __restrict__ src, bf16* __restrict__ dst,
                        int OC, int C, int ICT, int NP, int ICP, int n,
                        const int* __restrict__ fl) {
  int isb = *fl;
  int i = blockIdx.x * blockDim.x + threadIdx.x;
  if (i >= n) return;
  int s = i / (NP * ICP);
  int r = i - s * NP * ICP;
  int oc = r / ICP, icp = r - oc * ICP;
  float v = 0.0f;
  if (oc < OC) {
    int ic = -1;
    if (icp < C) ic = icp;
    else if (icp < 2 * C) ic = icp - C + C + 2;
    else if (icp < 2 * C + 2) ic = icp - 2 * C + C;
    if (ic >= 0 && ic < ICT) v = ldw(src, ((long)oc * ICT + ic) * 9 + s, isb);
  }
  dst[i] = f2bf(v);
}

// feats [F][C][HW] -> pixel-major bf16 [F][HW][C]; one thread per 8-channel group
__global__ void k_trans_feats(const void* __restrict__ in, bf16* __restrict__ Fp,
                              int F, int C, int HW, const int* __restrict__ fl) {
  int isb = *fl;
  int cpg = C >> 3;
  int n = F * HW * cpg;
  int i = blockIdx.x * blockDim.x + threadIdx.x;
  if (i >= n) return;
  int p = i % HW;
  int rem = i / HW;
  int c8 = rem % cpg;
  int f = rem / cpg;
  long base = (long)f * C * HW + (long)(c8 * 8) * HW + p;
  union { unsigned short u[8]; uint4 v; } pk;
#pragma unroll
  for (int j = 0; j < 8; ++j) pk.u[j] = bfr(ldw(in, base + (long)j * HW, isb));
  *(uint4*)((unsigned short*)Fp + ((long)f * HW + p) * C + c8 * 8) = pk.v;
}

// ---------------- decoder conv1: single-wave, barrier-free, spill-free ----------------
// One wave per block, 16 px x 16 outs. A staged in LDS per kc (<=16 staging VGPRs live);
// W fragments loaded DIRECTLY from global as MFMA operands (no LDS, no reg buffer, L2
// resident). No __syncthreads (within-wave LDS ordering). launch_bounds(64,2) caps VGPR
// at 256 -> no spill, >=8 waves/CU for TLP latency hiding.
template <int C, int ICP, int NP, int WW, int LGW>
__global__ __launch_bounds__(64, 2) void k_conv1d(
    const bf16* __restrict__ Fp, const float* __restrict__ flow,
    const bf16* __restrict__ Wp, const float* __restrict__ bias,
    bf16* __restrict__ out) {
  constexpr int HH = WW, HW = WW * WW;
  constexpr int ACW = 18, APX = 54;
  constexpr int NK = ICP / 32;
  __shared__ unsigned short As[APX][40];
  __shared__ int pofs[APX];
  __shared__ int doff[APX][4];
  __shared__ float dwt[APX][4];
  __shared__ float ffl[APX][2];
  int ln = threadIdx.x;
  int quad = ln >> 4, l16 = ln & 15;
  int n0 = blockIdx.x * 16, m0 = blockIdx.y * 16, b = blockIdx.z;
  int py0 = m0 >> LGW, px0 = m0 & (WW - 1);
  const unsigned short* fcur = (const unsigned short*)Fp + (long)b * HW * C;
  const unsigned short* fnxt = (const unsigned short*)Fp + (long)(b + 1) * HW * C;
  const float* fl = flow + (long)b * 2 * HW;
  // ---- per-pixel descriptors (lanes 0..53) ----
  if (ln < APX) {
    int sr = ln / ACW, sc = ln - sr * ACW;
    int py = py0 + sr - 1, px = px0 + sc - 1;
    bool in = py >= 0 && py < HH && px >= 0 && px < WW;
    int p = in ? (py * WW + px) : 0;
    pofs[ln] = in ? p * C : -1;
    float fx = in ? fl[p] : 0.0f, fy = in ? fl[HW + p] : 0.0f;
    float x = fminf(fmaxf((float)px + fx, 0.0f), (float)(WW - 1));
    float y = fminf(fmaxf((float)py + fy, 0.0f), (float)(HH - 1));
    int x0 = (int)floorf(x), y0 = (int)floorf(y);
    int x1 = min(x0 + 1, WW - 1), y1 = min(y0 + 1, HH - 1);
    float wx = x - (float)x0, wy = y - (float)y0;
    dwt[ln][0] = in ? (1 - wx) * (1 - wy) : 0.0f;
    dwt[ln][1] = in ? wx * (1 - wy) : 0.0f;
    dwt[ln][2] = in ? (1 - wx) * wy : 0.0f;
    dwt[ln][3] = in ? wx * wy : 0.0f;
    doff[ln][0] = (y0 * WW + x0) * C; doff[ln][1] = (y0 * WW + x1) * C;
    doff[ln][2] = (y1 * WW + x0) * C; doff[ln][3] = (y1 * WW + x1) * C;
    ffl[ln][0] = in ? fx : 0.0f; ffl[ln][1] = in ? fy : 0.0f;
  }
  // per-lane W row base for direct fragment loads
  const unsigned short* wrow = (const unsigned short*)Wp + (long)(n0 + l16) * ICP + quad * 8;
  f32x4 ac0 = {}, ac1 = {}, ac2 = {};
  for (int kc = 0; kc < NK; ++kc) {
    int chb = kc * 32;
    // ---- stage A chunk kc into LDS (small register footprint) ----
    if (chb < C) {
      uint4 arg[4];
#pragma unroll
      for (int j = 0; j < 4; ++j) {
        int idx = ln + j * 64;
        if (idx < APX * 4) {
          int ap = idx >> 2, c4 = idx & 3;
          int po = pofs[ap];
          uint4 z = {0, 0, 0, 0};
          arg[j] = (po >= 0) ? *(const uint4*)(fcur + po + chb + c4 * 8) : z;
        }
      }
#pragma unroll
      for (int j = 0; j < 4; ++j) {
        int idx = ln + j * 64;
        if (idx < APX * 4) {
          int ap = idx >> 2, c4 = idx & 3;
          *(uint4*)&As[ap][c4 * 8] = arg[j];
        }
      }
    } else if (chb < 2 * C) {
#pragma unroll
      for (int j = 0; j < 4; ++j) {
        int idx = ln + j * 64;
        if (idx < APX * 4) {
          int ap = idx >> 2, c4 = idx & 3;
          int c = chb - C + c4 * 8;
          uint4 v0 = *(const uint4*)(fnxt + doff[ap][0] + c);
          uint4 v1 = *(const uint4*)(fnxt + doff[ap][1] + c);
          uint4 v2 = *(const uint4*)(fnxt + doff[ap][2] + c);
          uint4 v3 = *(const uint4*)(fnxt + doff[ap][3] + c);
          float q0 = dwt[ap][0], q1 = dwt[ap][1], q2 = dwt[ap][2], q3 = dwt[ap][3];
          union { unsigned short u[8]; uint4 v; } a0 = {.v = v0}, a1 = {.v = v1},
                                                  a2 = {.v = v2}, a3 = {.v = v3}, o;
#pragma unroll
          for (int e = 0; e < 8; ++e)
            o.u[e] = bfr(shf(a0.u[e]) * q0 + shf(a1.u[e]) * q1 +
                         shf(a2.u[e]) * q2 + shf(a3.u[e]) * q3);
          *(uint4*)&As[ap][c4 * 8] = o.v;
        }
      }
    } else {
#pragma unroll
      for (int j = 0; j < 4; ++j) {
        int idx = ln + j * 64;
        if (idx < APX * 4) {
          int ap = idx >> 2, c4 = idx & 3;
          union { unsigned short u[8]; uint4 v; } o = { .v = {0, 0, 0, 0} };
          if (c4 == 0) { o.u[0] = bfr(ffl[ap][0]); o.u[1] = bfr(ffl[ap][1]); }
          *(uint4*)&As[ap][c4 * 8] = o.v;
        }
      }
    }
    // ---- MFMA: A from LDS, W fragments direct from global (L2 hits) ----
#pragma unroll
    for (int s = 0; s < 9; ++s) {
      int ky = s / 3, kx = s - ky * 3;
      bf16x8 af = *(const bf16x8*)&As[ky * ACW + l16 + kx][quad * 8];
      bf16x8 wf = *(const bf16x8*)(wrow + (long)s * NP * ICP + chb);
      if (s % 3 == 0)      ac0 = __builtin_amdgcn_mfma_f32_16x16x32_bf16(af, wf, ac0, 0, 0, 0);
      else if (s % 3 == 1) ac1 = __builtin_amdgcn_mfma_f32_16x16x32_bf16(af, wf, ac1, 0, 0, 0);
      else                 ac2 = __builtin_amdgcn_mfma_f32_16x16x32_bf16(af, wf, ac2, 0, 0, 0);
    }
  }
  int n = n0 + l16;
  float bv = bias[n];
  long rowbase = (long)b * (HH + 2) * (WW + 2) + (long)(py0 + 1) * (WW + 2);
#pragma unroll
  for (int r = 0; r < 4; ++r) {
    int px = px0 + quad * 4 + r;
    float v = gelu_exact(ac0[r] + ac1[r] + ac2[r] + bv);
    ((unsigned short*)out)[(rowbase + px + 1) * NP + n] = bfr(v);
  }
}

// ---------------- decoder conv2: wave-per-pixel dual dot (N=2, K=9*C) ----------------
template <int C, int WW, int LGW>
__global__ __launch_bounds__(256) void k_conv2_dot(
    const bf16* __restrict__ mid, const bf16* __restrict__ Wq,
    const float* __restrict__ bias, float* __restrict__ cur) {
  constexpr int HH = WW;
  constexpr int HW = HH * WW;
  constexpr int Wp2 = WW + 2;
  constexpr int CPL = C / 64;  // channels per lane (2 or 1)
  int tid = threadIdx.x, wv = tid >> 6, ln = tid & 63;
  int gw = blockIdx.x * 4 + wv;
  int b = gw >> (2 * LGW);
  int p = gw & (HW - 1);
  int py = p >> LGW, px = p & (WW - 1);
  float r0 = cur[((long)b * 2 + 0) * HW + p];
  float r1 = cur[((long)b * 2 + 1) * HW + p];
  float b0 = bias[0], b1 = bias[1];
  const unsigned short* base = (const unsigned short*)mid +
      ((long)b * (HH + 2) * Wp2 + (long)py * Wp2 + px) * C + ln * CPL;
  const unsigned short* wb = (const unsigned short*)Wq + ln * CPL;
  float s0 = 0.0f, s1 = 0.0f;
#pragma unroll
  for (int t = 0; t < 9; ++t) {
    int dy = t / 3, dx = t - dy * 3;
    const unsigned short* ar = base + ((long)dy * Wp2 + dx) * C;
    const unsigned short* w0r = wb + (long)(t * 16 + 0) * C;
    const unsigned short* w1r = wb + (long)(t * 16 + 1) * C;
    if (CPL == 2) {
      unsigned int a = *(const unsigned int*)ar;
      unsigned int q0 = *(const unsigned int*)w0r;
      unsigned int q1 = *(const unsigned int*)w1r;
      float a0 = shf((unsigned short)a), a1 = shf((unsigned short)(a >> 16));
      s0 += a0 * shf((unsigned short)q0) + a1 * shf((unsigned short)(q0 >> 16));
      s1 += a0 * shf((unsigned short)q1) + a1 * shf((unsigned short)(q1 >> 16));
    } else {
      float a0 = shf(ar[0]);
      s0 += a0 * shf(w0r[0]);
      s1 += a0 * shf(w1r[0]);
    }
  }
#pragma unroll
  for (int o = 32; o; o >>= 1) { s0 += __shfl_xor(s0, o); s1 += __shfl_xor(s1, o); }
  if (ln == 0) {
    cur[((long)b * 2 + 0) * HW + p] = s0 + b0 + r0;
    cur[((long)b * 2 + 1) * HW + p] = s1 + b1 + r1;
  }
}

// ---------------- local correlation from pixel-major bf16 Fp2, bf16 out, stride 64 -------
__global__ void k_corr(const bf16* __restrict__ Fp2, bf16* __restrict__ corrT) {
  __shared__ unsigned short f1r[128];
  int p = blockIdx.x;
  int b = blockIdx.y;
  int t = threadIdx.x;  // 64
  const unsigned short* f1 = (const unsigned short*)Fp2 + ((long)b * 1024 + p) * 128;
  if (t < 16) *(uint4*)&f1r[t * 8] = *(const uint4*)(f1 + t * 8);
  __syncthreads();
  long rowo = ((long)b * 1024 + p) * 64;
  if (t < 49) {
    int dy = t / 7 - 3, dx = t % 7 - 3;
    int h = p >> 5, w = p & 31;
    int p2 = (((h - dy) & 31) << 5) | ((w - dx) & 31);
    const unsigned short* f2 = (const unsigned short*)Fp2 + ((long)(b + 1) * 1024 + p2) * 128;
    float s = 0.0f;
    for (int c = 0; c < 128; c += 8) {
      union { unsigned short u[8]; uint4 v; } av = { .v = *(const uint4*)&f1r[c] };
      union { unsigned short u[8]; uint4 v; } bv = { .v = *(const uint4*)(f2 + c) };
#pragma unroll
      for (int j = 0; j < 8; ++j) s += shf(av.u[j]) * shf(bv.u[j]);
    }
    corrT[rowo + t] = f2bf(s * 0.08838834764831845f);
  } else {
    corrT[rowo + t] = f2bf(0.0f);
  }
}

// ---------------- unified MFMA bf16 GEMM, full-192 superchunk staging ----------------
// KT: compile-time K. BM: 64 (4 M-waves) or 32 (2 M-waves x 2 N-waves).
// AMODE: 0 = fp32 A; 1 = bf16 A; 2 = fused split-K attention merge (K=192);
// 3 = fp32 A with fused LayerNorm (K=192).
// VT: scatter V-region (n>=384) into vt[b][h][48][1024] (BM=64 only).
template <int KT, int BM, int ACT, bool HASRES, int AMODE, int OUTBF, int VT>
__global__ __launch_bounds__(256) void k_gemm_mfma2(
    const void* __restrict__ A, const void* __restrict__ W, long woff,
    const void* __restrict__ bias, long boff, const int* __restrict__ flb,
    const float* __restrict__ res, void* __restrict__ C,
    int M, int N, const int* __restrict__ fl,
    const unsigned short* __restrict__ mop, const float* __restrict__ mml,
    bf16* __restrict__ vtout,
    const void* __restrict__ lnw, long lnwoff,
    const void* __restrict__ lnb, long lnboff) {
  (void)M;
  int isb = *fl;
  constexpr int NKC = ((KT < 192) ? KT : 192) >> 5;  // 32-wide chunks per superchunk
  constexpr int WM = (BM == 64) ? 4 : 2;             // waves along M
  constexpr int NTW = (BM == 64) ? 4 : 2;            // n-tiles per wave
  constexpr int LPR = 256 / BM;                      // lanes per row (AMODE 2/3)
  constexpr int EPL = 192 / LPR;                     // elems per lane (AMODE 2/3)
  __shared__ unsigned short Asm[NKC][BM][40];
  __shared__ unsigned short Wsm[NKC][64][40];
  int tid = threadIdx.x;
  int wv = tid >> 6, ln = tid & 63;
  int quad = ln >> 4, l16 = ln & 15;
  int wm = wv % WM, wn = wv / WM;
  int m0 = blockIdx.y * BM, n0 = blockIdx.x * 64;
  f32x4 acc[NTW] = {};
  for (int s0 = 0; s0 < KT; s0 += 192) {
    if (s0) __syncthreads();
    // ---- stage W (64 cols x NKC*32) ----
    for (int i = tid; i < NKC * 256; i += 256) {
      int c4 = i & 3, r = (i >> 2) & 63, kc = i >> 8;
      long eo = woff + (long)(n0 + r) * KT + s0 + kc * 32 + c4 * 8;
      if (isb) {
        *(uint4*)&Wsm[kc][r][c4 * 8] = *(const uint4*)((const unsigned short*)W + eo);
      } else {
        const float* wp = (const float*)W + eo;
        float4 w0 = *(const float4*)wp;
        float4 w1 = *(const float4*)(wp + 4);
        union { unsigned short u[8]; uint4 v; } pk;
        pk.u[0] = bfr(w0.x); pk.u[1] = bfr(w0.y); pk.u[2] = bfr(w0.z); pk.u[3] = bfr(w0.w);
        pk.u[4] = bfr(w1.x); pk.u[5] = bfr(w1.y); pk.u[6] = bfr(w1.z); pk.u[7] = bfr(w1.w);
        *(uint4*)&Wsm[kc][r][c4 * 8] = pk.v;
      }
    }
    // ---- stage A ----
    if constexpr (AMODE == 1) {
      for (int i = tid; i < NKC * BM * 4; i += 256) {
        int c4 = i & 3, r = (i >> 2) % BM, kc = i / (BM * 4);
        const unsigned short* ap =
            (const unsigned short*)A + (long)(m0 + r) * KT + s0 + kc * 32 + c4 * 8;
        *(uint4*)&Asm[kc][r][c4 * 8] = *(const uint4*)ap;
      }
    } else if constexpr (AMODE == 0) {
      for (int i = tid; i < NKC * BM * 4; i += 256) {
        int c4 = i & 3, r = (i >> 2) % BM, kc = i / (BM * 4);
        const float* ap = (const float*)A + (long)(m0 + r) * KT + s0 + kc * 32 + c4 * 8;
        float4 a0 = *(const float4*)ap;
        float4 a1 = *(const float4*)(ap + 4);
        union { unsigned short u[8]; uint4 v; } pk;
        pk.u[0] = bfr(a0.x); pk.u[1] = bfr(a0.y); pk.u[2] = bfr(a0.z); pk.u[3] = bfr(a0.w);
        pk.u[4] = bfr(a1.x); pk.u[5] = bfr(a1.y); pk.u[6] = bfr(a1.z); pk.u[7] = bfr(a1.w);
        *(uint4*)&Asm[kc][r][c4 * 8] = pk.v;
      }
    } else if constexpr (AMODE == 3) {
      // fused LayerNorm over K=192; LPR lanes per row, EPL contiguous elems each
      int row = tid / LPR, j = tid % LPR;
      const float* xr = (const float*)A + (long)(m0 + row) * 192 + j * EPL;
      float av[EPL];
#pragma unroll
      for (int q4 = 0; q4 < EPL / 4; ++q4) {
        float4 v = *(const float4*)(xr + q4 * 4);
        av[q4 * 4 + 0] = v.x; av[q4 * 4 + 1] = v.y;
        av[q4 * 4 + 2] = v.z; av[q4 * 4 + 3] = v.w;
      }
      float sum = 0.0f;
#pragma unroll
      for (int q = 0; q < EPL; ++q) sum += av[q];
#pragma unroll
      for (int o = 1; o < LPR; o <<= 1) sum += __shfl_xor(sum, o);
      float mean = sum * (1.0f / 192.0f);
      float vs = 0.0f;
#pragma unroll
      for (int q = 0; q < EPL; ++q) { float d = av[q] - mean; vs += d * d; }
#pragma unroll
      for (int o = 1; o < LPR; o <<= 1) vs += __shfl_xor(vs, o);
      float rstd = rsqrtf(vs * (1.0f / 192.0f) + 1e-5f);
#pragma unroll
      for (int g = 0; g < EPL / 8; ++g) {
        int k = j * EPL + g * 8;
        union { unsigned short u[8]; uint4 v; } pk;
#pragma unroll
        for (int e = 0; e < 8; ++e) {
          float gg = ldw(lnw, lnwoff + k + e, isb);
          float bb = ldw(lnb, lnboff + k + e, isb);
          pk.u[e] = bfr((av[g * 8 + e] - mean) * rstd * gg + bb);
        }
        *(uint4*)&Asm[k >> 5][row][k & 31] = pk.v;
      }
    } else {
      // AMODE == 2: fused attention merge (4 split partials, bf16 O, fp32 m/l)
      int row = tid / LPR, j = tid % LPR;
      int m = m0 + row;
      int rr = m & 1023, bb = m >> 10;
#pragma unroll
      for (int g = 0; g < EPL / 8; ++g) {
        int k = j * EPL + g * 8;  // 8-run never crosses a head (48 % 8 == 0)
        int h = k / 48;
        int d0 = k - h * 48;
        long idx[4];
        float ms[4], ls[4];
        float Ms = -1e30f;
#pragma unroll
        for (int s = 0; s < 4; ++s) {
          idx[s] = (((long)s * 2 + bb) * 4 + h) * 1024 + rr;
          ms[s] = mml[idx[s] * 2];
          ls[s] = mml[idx[s] * 2 + 1];
          Ms = fmaxf(Ms, ms[s]);
        }
        float e[4], L = 0.0f;
#pragma unroll
        for (int s = 0; s < 4; ++s) { e[s] = __expf(ms[s] - Ms); L += ls[s] * e[s]; }
        float invL = 1.0f / L;
        union { unsigned short u[8]; uint4 v; } pk;
#pragma unroll
        for (int e2 = 0; e2 < 8; ++e2) {
          float o = 0.0f;
#pragma unroll
          for (int s = 0; s < 4; ++s) o += shf(mop[idx[s] * 48 + d0 + e2]) * e[s];
          pk.u[e2] = bfr(o * invL);
        }
        *(uint4*)&Asm[k >> 5][row][k & 31] = pk.v;
      }
    }
    __syncthreads();
#pragma unroll
    for (int kc = 0; kc < NKC; ++kc) {
      bf16x8 af = *(const bf16x8*)&Asm[kc][wm * 16 + l16][quad * 8];
#pragma unroll
      for (int nt = 0; nt < NTW; ++nt) {
        bf16x8 wf = *(const bf16x8*)&Wsm[kc][(wn * NTW + nt) * 16 + l16][quad * 8];
        acc[nt] = __builtin_amdgcn_mfma_f32_16x16x32_bf16(af, wf, acc[nt], 0, 0, 0);
      }
    }
  }
  int isbb = *flb;
#pragma unroll
  for (int nt = 0; nt < NTW; ++nt) {
    int n = n0 + (wn * NTW + nt) * 16 + l16;
    float bv = ldw(bias, boff + n, isbb);
#pragma unroll
    for (int r = 0; r < 4; ++r) {
      int m = m0 + wm * 16 + quad * 4 + r;
      float v = acc[nt][r] + bv;
      if (HASRES) v += res[(long)m * N + n];
      if (ACT == 1) v = gelu_exact(v);
      if (OUTBF) ((bf16*)C)[(long)m * N + n] = f2bf(v);
      else ((float*)C)[(long)m * N + n] = v;
      if constexpr (VT) {
        if (n >= 384) {
          int hh = (n - 384) / 48, dd = (n - 384) % 48;
          int row = m & 1023, bb = m >> 10;
          vtout[((long)(bb * 4 + hh) * 48 + dd) * 1024 + row] = f2bf(v);
        }
      }
    }
  }
}

// ---------------- head second layer: wave-per-output dot (N=2, K=192) ----------------
__global__ __launch_bounds__(256) void k_head2(const float* __restrict__ A,
                                               const void* __restrict__ W,
                                               const void* __restrict__ bias,
                                               float* __restrict__ C,
                                               const int* __restrict__ fl) {
  int isb = *fl;
  int wv = threadIdx.x >> 6, ln = threadIdx.x & 63;
  int gw = blockIdx.x * 4 + wv;  // 0..4095
  int m = gw >> 1, n = gw & 1;
  const float* a = A + (long)m * 192;
  float s = 0.0f;
#pragma unroll
  for (int q = 0; q < 3; ++q) {
    int j = ln + q * 64;
    s += a[j] * ldw(W, (long)n * 192 + j, isb);
  }
  for (int o = 32; o; o >>= 1) s += __shfl_xor(s, o);
  if (ln == 0) {
    int b = m >> 10, p = m & 1023;
    C[((long)b * 2 + n) * 1024 + p] = s + ldw(bias, n, isb);
  }
}

// ---------------- MFMA flash attention, split-K (4 splits of 4 chunks) -------------------
__global__ __launch_bounds__(256) void k_attn_mfma(const bf16* __restrict__ qkv,
                                                   const bf16* __restrict__ vt,
                                                   unsigned short* __restrict__ opart,
                                                   float* __restrict__ ml) {
  __shared__ unsigned short Qs[64][72];
  __shared__ unsigned short Ks[64][72];
  __shared__ unsigned short Vs[48][72];
  __shared__ unsigned short Ps[64][72];
  int tid = threadIdx.x;
  int wv = tid >> 6, ln = tid & 63, quad = ln >> 4, l16 = ln & 15;
  int h = blockIdx.y, b = blockIdx.z;
  int qt = blockIdx.x >> 2, s = blockIdx.x & 3;
  int q0 = qt * 64;
  const unsigned short* qp = (const unsigned short*)qkv + (long)b * 1024 * 576;
  const unsigned short* vp = (const unsigned short*)vt + ((long)(b * 4 + h) * 48) * 1024;
  for (int i = tid; i < 384; i += 256) {
    int r = i / 6, c = i % 6;
    *(uint4*)&Qs[r][c * 8] = *(const uint4*)(qp + (long)(q0 + r) * 576 + h * 48 + c * 8);
  }
  for (int i = tid; i < 128; i += 256) {
    int r = i >> 1, c = 6 + (i & 1);
    uint4 z = {0, 0, 0, 0};
    *(uint4*)&Qs[r][c * 8] = z;
  }
  float m[4] = {-1e30f, -1e30f, -1e30f, -1e30f};
  float l[4] = {0.0f, 0.0f, 0.0f, 0.0f};
  f32x4 accO[3] = {};
  const float SC = 0.14433756729740643f;
  for (int kc = s * 4; kc < s * 4 + 4; ++kc) {
    int k0 = kc * 64;
    for (int i = tid; i < 384; i += 256) {
      int r = i / 6, c = i % 6;
      *(uint4*)&Ks[r][c * 8] = *(const uint4*)(qp + (long)(k0 + r) * 576 + 192 + h * 48 + c * 8);
    }
    for (int i = tid; i < 128; i += 256) {
      int r = i >> 1, c = 6 + (i & 1);
      uint4 z = {0, 0, 0, 0};
      *(uint4*)&Ks[r][c * 8] = z;
    }
    for (int i = tid; i < 384; i += 256) {
      int d = i >> 3, c = i & 7;
      *(uint4*)&Vs[d][c * 8] = *(const uint4*)(vp + (long)d * 1024 + k0 + c * 8);
    }
    __syncthreads();
    f32x4 accS[4] = {};
    bf16x8 a0 = *(const bf16x8*)&Qs[wv * 16 + l16][quad * 8];
    bf16x8 a1 = *(const bf16x8*)&Qs[wv * 16 + l16][32 + quad * 8];
#pragma unroll
    for (int ct = 0; ct < 4; ++ct) {
      bf16x8 b0 = *(const bf16x8*)&Ks[ct * 16 + l16][quad * 8];
      bf16x8 b1 = *(const bf16x8*)&Ks[ct * 16 + l16][32 + quad * 8];
      accS[ct] = __builtin_amdgcn_mfma_f32_16x16x32_bf16(a0, b0, accS[ct], 0, 0, 0);
      accS[ct] = __builtin_amdgcn_mfma_f32_16x16x32_bf16(a1, b1, accS[ct], 0, 0, 0);
    }
#pragma unroll
    for (int r = 0; r < 4; ++r) {
      float s0 = accS[0][r] * SC, s1 = accS[1][r] * SC;
      float s2 = accS[2][r] * SC, s3 = accS[3][r] * SC;
      float mx = fmaxf(fmaxf(s0, s1), fmaxf(s2, s3));
      for (int o = 8; o; o >>= 1) mx = fmaxf(mx, __shfl_xor(mx, o));
      float mn = fmaxf(m[r], mx);
      float alpha = __expf(m[r] - mn);
      float p0 = __expf(s0 - mn), p1 = __expf(s1 - mn);
      float p2 = __expf(s2 - mn), p3 = __expf(s3 - mn);
      float rs = p0 + p1 + p2 + p3;
      for (int o = 8; o; o >>= 1) rs += __shfl_xor(rs, o);
      m[r] = mn;
      l[r] = l[r] * alpha + rs;
      accO[0][r] *= alpha; accO[1][r] *= alpha; accO[2][r] *= alpha;
      int prow = wv * 16 + quad * 4 + r;
      Ps[prow][l16]      = bfr(p0);
      Ps[prow][16 + l16] = bfr(p1);
      Ps[prow][32 + l16] = bfr(p2);
      Ps[prow][48 + l16] = bfr(p3);
    }
    bf16x8 pf0 = *(const bf16x8*)&Ps[wv * 16 + l16][quad * 8];
    bf16x8 pf1 = *(const bf16x8*)&Ps[wv * 16 + l16][32 + quad * 8];
#pragma unroll
    for (int ct = 0; ct < 3; ++ct) {
      bf16x8 v0 = *(const bf16x8*)&Vs[ct * 16 + l16][quad * 8];
      bf16x8 v1 = *(const bf16x8*)&Vs[ct * 16 + l16][32 + quad * 8];
      accO[ct] = __builtin_amdgcn_mfma_f32_16x16x32_bf16(pf0, v0, accO[ct], 0, 0, 0);
      accO[ct] = __builtin_amdgcn_mfma_f32_16x16x32_bf16(pf1, v1, accO[ct], 0, 0, 0);
    }
    __syncthreads();
  }
  long base = (((long)s * 2 + b) * 4 + h) * 1024;
#pragma unroll
  for (int r = 0; r < 4; ++r) {
    int row = q0 + wv * 16 + quad * 4 + r;
#pragma unroll
    for (int ct = 0; ct < 3; ++ct)
      opart[(base + row) * 48 + ct * 16 + l16] = bfr(accO[ct][r]);
    if (l16 == 0) {
      ml[(base + row) * 2]     = m[r];
      ml[(base + row) * 2 + 1] = l[r];
    }
  }
}

// ---------------- EMA / upsample / out ----------------
__global__ void k_ema(float* __restrict__ x) {
  int i = blockIdx.x * blockDim.x + threadIdx.x;
  if (i < 196608) x[196608 + i] = 0.8f * x[196608 + i] + 0.2f * x[i];
}

__global__ void k_upsample(const float* __restrict__ in, float* __restrict__ out) {
  int i = blockIdx.x * blockDim.x + threadIdx.x;
  if (i >= 2 * 2 * 64 * 64) return;
  int p = i & 4095;
  int bc = i >> 12;
  int oy = p >> 6, ox = p & 63;
  float sx = ox * (31.0f / 63.0f), sy = oy * (31.0f / 63.0f);
  int x0 = (int)sx, y0 = (int)sy;
  int x1 = min(x0 + 1, 31), y1 = min(y0 + 1, 31);
  float wx = sx - x0, wy = sy - y0;
  const float* ic = in + (long)bc * 1024;
  out[i] = ic[y0 * 32 + x0] * (1 - wx) * (1 - wy) + ic[y0 * 32 + x1] * wx * (1 - wy)
         + ic[y1 * 32 + x0] * (1 - wx) * wy      + ic[y1 * 32 + x1] * wx * wy;
}

__global__ void k_out(const float* __restrict__ cur2, void* __restrict__ out,
                      const int* __restrict__ fl) {
  int isb = *fl;
  int i = blockIdx.x * blockDim.x + threadIdx.x;
  if (i < 16384) {
    if (isb) ((bf16*)out)[i] = f2bf(cur2[i]);
    else ((float*)out)[i] = cur2[i];
  }
}

extern "C" void kernel_launch(void* const* d_in, const int* in_sizes, int n_in,
                              void* d_out, int out_size, void* d_ws, size_t ws_size,
                              hipStream_t stream) {
  const void* feats_l1 = d_in[0];
  const void* feats_l2 = d_in[1];
  const void* tok_w = d_in[3];
  const void* tok_b = d_in[4];
  const void* lcm_ln1_w = d_in[5];
  const void* lcm_ln1_b = d_in[6];
  const void* lcm_in_w  = d_in[7];
  const void* lcm_in_b  = d_in[8];
  const void* lcm_out_w = d_in[9];
  const void* lcm_out_b = d_in[10];
  const void* lcm_ln2_w = d_in[11];
  const void* lcm_ln2_b = d_in[12];
  const void* lcm_mlp_w1 = d_in[13];
  const void* lcm_mlp_b1 = d_in[14];
  const void* lcm_mlp_w2 = d_in[15];
  const void* lcm_mlp_b2 = d_in[16];
  const void* gtr_ln1_w = d_in[17];
  const void* gtr_ln1_b = d_in[18];
  const void* gtr_in_w  = d_in[19];
  const void* gtr_in_b  = d_in[20];
  const void* gtr_out_w = d_in[21];
  const void* gtr_out_b = d_in[22];
  const void* gtr_ln2_w = d_in[23];
  const void* gtr_ln2_b = d_in[24];
  const void* gtr_mlp_w1 = d_in[25];
  const void* gtr_mlp_b1 = d_in[26];
  const void* gtr_mlp_w2 = d_in[27];
  const void* gtr_mlp_b2 = d_in[28];
  const void* head_w1 = d_in[29];
  const void* head_b1 = d_in[30];
  const void* head_w2 = d_in[31];
  const void* head_b2 = d_in[32];
  const void* ref1_w1 = d_in[33];
  const void* ref1_b1 = d_in[34];
  const void* ref1_w2 = d_in[35];
  const void* ref1_b2 = d_in[36];
  const void* ref0_w1 = d_in[37];
  const void* ref0_b1 = d_in[38];
  const void* ref0_w2 = d_in[39];
  const void* ref0_b2 = d_in[40];
  (void)ws_size; (void)n_in; (void)in_sizes; (void)out_size;

  // ---- workspace layout (f-eq units; ~16.8 MB) ----
  int* flag = (int*)d_ws;
  int* oneflag = (int*)d_ws + 2;
  float* wsf = (float*)d_ws;
  float* F2   = wsf + 16;             // 393216 (spare; layout stability)
  float* rA   = F2 + 393216;          // 786432 : opart bf16
  float* rX   = rA + 786432;          // 393216 : residual x
  float* rT   = rX + 393216;          // 393216 : head-hidden | mid0packed
  float* rY   = rT + 393216;          // 393216 : mlbuf | mid1packed
  float* big  = rY + 393216;          // 1572864: qkv/vt/hid [0,851968) | Fp2+Fp1 tail
  float* fv   = big + 1572864;        // 4096 (unused)
  float* cur  = fv + 4096;            // 4096
  float* cur2 = cur + 4096;           // 16384
  float* cb1a = cur2 + 16384;         // 128
  float* cb1b = cb1a + 128;           // 16
  float* cb0a = cb1b + 16;            // 64
  float* cb0b = cb0a + 64;            // 16
  bf16* wtok  = (bf16*)(cb0b + 16);   // 12288 shorts
  float* wpk  = cb0b + 16 + 6144;
  bf16* w1p1 = (bf16*)wpk;            // 331776 shorts
  bf16* w1p2 = (bf16*)(wpk + 165888); // 18432 shorts
  bf16* w0p1 = (bf16*)(wpk + 175104); // 92160 shorts
  bf16* w0p2 = (bf16*)(wpk + 221184); // 9216 shorts

  float* x = rX;
  bf16* corrTb = (bf16*)big;
  bf16* qkvbb  = (bf16*)big;
  bf16* vtb    = (bf16*)(big + 655360);
  bf16* hidb   = (bf16*)big;
  unsigned short* opart = (unsigned short*)rA;  // [4][2][4][1024][48] bf16
  float* mlbuf = rY;                            // [4][2][4][1024][2] fp32
  float* headh = rT;
  bf16* mid0p = (bf16*)rT;
  bf16* mid1p = (bf16*)rY;
  bf16* Fp2   = (bf16*)(big + 851968);   // [3][1024][128] = 393216 shorts
  bf16* Fp1   = (bf16*)(big + 1048576);  // [3][4096][64]  = 786432 shorts

  k_detect<<<1, 256, 0, stream>>>((const unsigned short*)feats_l1, flag);
  k_setone<<<1, 1, 0, stream>>>(oneflag);
  k_cvt<<<1, 256, 0, stream>>>(ref1_b1, cb1a, 128, flag);
  k_cvt<<<1, 256, 0, stream>>>(ref1_b2, cb1b, 2, flag);
  k_cvt<<<1, 256, 0, stream>>>(ref0_b1, cb0a, 64, flag);
  k_cvt<<<1, 256, 0, stream>>>(ref0_b2, cb0b, 2, flag);
  k_padtokw<<<48, 256, 0, stream>>>(tok_w, wtok, flag);
  k_packw<<<1296, 256, 0, stream>>>(ref1_w1, w1p1, 128, 128, 258, 128, 288, 331776, flag);
  k_packw<<<72, 256, 0, stream>>>(ref1_w2, w1p2, 2, 128, 128, 16, 128, 18432, flag);
  k_packw<<<360, 256, 0, stream>>>(ref0_w1, w0p1, 64, 64, 130, 64, 160, 92160, flag);
  k_packw<<<36, 256, 0, stream>>>(ref0_w2, w0p2, 2, 64, 64, 16, 64, 9216, flag);
  // pixel-major frames up front (big tail survives qkv/hid which use [0,851968))
  k_trans_feats<<<192, 256, 0, stream>>>(feats_l2, Fp2, 3, 128, 1024, flag);
  k_trans_feats<<<384, 256, 0, stream>>>(feats_l1, Fp1, 3, 64, 4096, flag);

  // ---- tokens: corr (from Fp2) then tokenizer GEMM (BM=32 for occupancy) ----
  k_corr<<<dim3(1024, 2), 64, 0, stream>>>(Fp2, corrTb);
  k_gemm_mfma2<64, 32, 0, false, 1, 0, 0><<<dim3(3, 64), 256, 0, stream>>>(
      corrTb, wtok, 0, tok_b, 192, flag, nullptr, x, 2048, 192, oneflag,
      nullptr, nullptr, nullptr, nullptr, 0, nullptr, 0);

  auto run_block = [&](const void* ln1w, long o1, const void* ln1b, long o2,
                       const void* inw, long o3, const void* inb, long o4,
                       const void* ow, long o5, const void* ob, long o6,
                       const void* ln2w, long o7, const void* ln2b, long o8,
                       const void* w1, long o9, const void* b1, long o10,
                       const void* w2, long o11, const void* b2, long o12) {
    // fused LN1 + qkv GEMM: bf16 out + fused V-transpose scatter
    k_gemm_mfma2<192, 64, 0, false, 3, 1, 1><<<dim3(9, 32), 256, 0, stream>>>(
        x, inw, o3, inb, o4, flag, nullptr, qkvbb, 2048, 576, flag,
        nullptr, nullptr, vtb, ln1w, o1, ln1b, o2);
    k_attn_mfma<<<dim3(64, 4, 2), 256, 0, stream>>>(qkvbb, vtb, opart, mlbuf);
    // out-proj GEMM: fused 4-way split-K merge as A-operand (BM=32)
    k_gemm_mfma2<192, 32, 0, true, 2, 0, 0><<<dim3(3, 64), 256, 0, stream>>>(
        nullptr, ow, o5, ob, o6, flag, x, x, 2048, 192, flag,
        opart, mlbuf, nullptr, nullptr, 0, nullptr, 0);
    // fused LN2 + mlp1 GEMM
    k_gemm_mfma2<192, 64, 1, false, 3, 1, 0><<<dim3(12, 32), 256, 0, stream>>>(
        x, w1, o9, b1, o10, flag, nullptr, hidb, 2048, 768, flag,
        nullptr, nullptr, nullptr, ln2w, o7, ln2b, o8);
    // mlp2 (K=768), BM=32
    k_gemm_mfma2<768, 32, 0, true, 1, 0, 0><<<dim3(3, 64), 256, 0, stream>>>(
        hidb, w2, o11, b2, o12, flag, x, x, 2048, 192, flag,
        nullptr, nullptr, nullptr, nullptr, 0, nullptr, 0);
  };

  for (int i = 0; i < 6; ++i) {
    run_block(lcm_ln1_w, (long)i * 192, lcm_ln1_b, (long)i * 192,
              lcm_in_w, (long)i * 110592, lcm_in_b, (long)i * 576,
              lcm_out_w, (long)i * 36864, lcm_out_b, (long)i * 192,
              lcm_ln2_w, (long)i * 192, lcm_ln2_b, (long)i * 192,
              lcm_mlp_w1, (long)i * 147456, lcm_mlp_b1, (long)i * 768,
              lcm_mlp_w2, (long)i * 147456, lcm_mlp_b2, (long)i * 192);
  }
  k_ema<<<768, 256, 0, stream>>>(x);

  for (int i = 0; i < 2; ++i) {
    run_block(gtr_ln1_w, (long)i * 192, gtr_ln1_b, (long)i * 192,
              gtr_in_w, (long)i * 110592, gtr_in_b, (long)i * 576,
              gtr_out_w, (long)i * 36864, gtr_out_b, (long)i * 192,
              gtr_ln2_w, (long)i * 192, gtr_ln2_b, (long)i * 192,
              gtr_mlp_w1, (long)i * 147456, gtr_mlp_b1, (long)i * 768,
              gtr_mlp_w2, (long)i * 147456, gtr_mlp_b2, (long)i * 192);
  }

  // ---- head -> coarse flow (wave-dot second layer writes [b][2][1024]) ----
  k_gemm_mfma2<192, 32, 1, false, 0, 0, 0><<<dim3(3, 64), 256, 0, stream>>>(
      x, head_w1, 0, head_b1, 0, flag, nullptr, headh, 2048, 192, flag,
      nullptr, nullptr, nullptr, nullptr, 0, nullptr, 0);
  k_head2<<<1024, 256, 0, stream>>>(headh, head_w2, head_b2, cur, flag);

  // ---- decoder prep: zero mid buffers (borders must stay 0) ----
  k_zerosh<<<768, 256, 0, stream>>>((unsigned short*)rT, 196608);

  // ---- decoder level 1 (32x32): C=128, ICP=288, OC=128 ----
  for (int it = 0; it < 4; ++it) {
    k_conv1d<128, 288, 128, 32, 5><<<dim3(8, 64, 2), 64, 0, stream>>>(
        Fp2, cur, w1p1, cb1a, mid1p);
    k_conv2_dot<128, 32, 5><<<512, 256, 0, stream>>>(mid1p, w1p2, cb1b, cur);
  }
  k_upsample<<<64, 256, 0, stream>>>(cur, cur2);

  // ---- decoder level 0 (64x64): C=64, ICP=160, OC=64 ----
  for (int it = 0; it < 4; ++it) {
    k_conv1d<64, 160, 64, 64, 6><<<dim3(4, 256, 2), 64, 0, stream>>>(
        Fp1, cur2, w0p1, cb0a, mid0p);
    k_conv2_dot<64, 64, 6><<<2048, 256, 0, stream>>>(mid0p, w0p2, cb0b, cur2);
  }

  k_out<<<64, 256, 0, stream>>>(cur2, d_out, flag);
}